// Round 8
// baseline (422.711 us; speedup 1.0000x reference)
//
#include <hip/hip_runtime.h>

#define B_ 32
#define D_ 128
#define LC 2048
#define LQ 512
#define CCH 16   // col-partials count == LC/128 (one per k_S c-tile)
#define RCH 4    // row-partials count == LQ/128 (one per k_S q-tile)

#define NEGINF (-3.0e38f)

typedef __attribute__((ext_vector_type(8))) short bf16x8;
typedef __attribute__((ext_vector_type(4))) float f32x4;
typedef __attribute__((ext_vector_type(8))) unsigned short us8;
typedef __attribute__((ext_vector_type(8))) _Float16 f16x8;

__device__ __forceinline__ unsigned short bf16rne(float x) {
    unsigned int u = __float_as_uint(x);
    u = (u + 0x7FFFu + ((u >> 16) & 1u)) >> 16;
    return (unsigned short)u;
}

__device__ __forceinline__ void gll16(const void* g, void* l) {
    __builtin_amdgcn_global_load_lds((const __attribute__((address_space(1))) void*)g,
                                     (__attribute__((address_space(3))) void*)l, 16, 0, 0);
}

// ---------- K0: outv[b,x] = sum_d X[b,d,x] * w[d] ----------
__global__ void k_dotw(const float* __restrict__ X, const float* __restrict__ w,
                       float* __restrict__ outv, int L) {
    int idx = blockIdx.x * 256 + threadIdx.x;
    int b = idx / L, x = idx - b * L;
    const float* Xp = X + (size_t)b * D_ * L + x;
    float acc = 0.f;
#pragma unroll 8
    for (int dd = 0; dd < D_; ++dd) acc += Xp[(size_t)dd * L] * w[dd];
    outv[idx] = acc;
}

// ---------- prep C ----------
__global__ void k_prep_C(const float* __restrict__ C, const float* __restrict__ wmul,
                         short* __restrict__ Ctw, short* __restrict__ Cb16) {
    int b = blockIdx.y, c0 = blockIdx.x * 64;
    __shared__ float Tf[128][65];
    __shared__ float wm[128];
    int t = threadIdx.x;
    if (t < 128) wm[t] = wmul[t];
    const float* Cb = C + (size_t)b * D_ * LC;
#pragma unroll
    for (int i = 0; i < 8; ++i) {
        int idx = t + i * 256;
        int d = idx >> 4, c4 = idx & 15;
        float4 v = *(const float4*)(Cb + (size_t)d * LC + c0 + c4 * 4);
        Tf[d][c4 * 4 + 0] = v.x; Tf[d][c4 * 4 + 1] = v.y;
        Tf[d][c4 * 4 + 2] = v.z; Tf[d][c4 * 4 + 3] = v.w;
        ushort4 cv;
        cv.x = bf16rne(v.x); cv.y = bf16rne(v.y); cv.z = bf16rne(v.z); cv.w = bf16rne(v.w);
        *(ushort4*)(Cb16 + ((size_t)b * D_ + d) * LC + c0 + c4 * 4) = cv;
    }
    __syncthreads();
    int c_l = t & 63, g = t >> 6;
    unsigned short u[32];
#pragma unroll
    for (int j = 0; j < 32; ++j) {
        int d = g * 32 + j;
        u[j] = bf16rne(Tf[d][c_l] * wm[d]);
    }
    short* dst = Ctw + ((size_t)b * LC + c0 + c_l) * D_ + g * 32;
#pragma unroll
    for (int k = 0; k < 4; ++k) *(us8*)(dst + k * 8) = *(const us8*)&u[k * 8];
}

// ---------- prep Q ----------
__global__ void k_prep_Q(const float* __restrict__ Q, short* __restrict__ Qt16,
                         short* __restrict__ Wf) {
    int b = blockIdx.y, q0 = blockIdx.x * 64;
    __shared__ float Tf[128][65];
    int t = threadIdx.x;
    const float* Qb = Q + (size_t)b * D_ * LQ;
#pragma unroll
    for (int i = 0; i < 8; ++i) {
        int idx = t + i * 256;
        int d = idx >> 4, q4 = idx & 15;
        float4 v = *(const float4*)(Qb + (size_t)d * LQ + q0 + q4 * 4);
        Tf[d][q4 * 4 + 0] = v.x; Tf[d][q4 * 4 + 1] = v.y;
        Tf[d][q4 * 4 + 2] = v.z; Tf[d][q4 * 4 + 3] = v.w;
        ushort4 cv;
        cv.x = bf16rne(v.x); cv.y = bf16rne(v.y); cv.z = bf16rne(v.z); cv.w = bf16rne(v.w);
        *(ushort4*)(Wf + ((size_t)b * 256 + d) * LQ + q0 + q4 * 4) = cv;
    }
    __syncthreads();
    int q_l = t & 63, g = t >> 6;
    unsigned short u[32];
#pragma unroll
    for (int j = 0; j < 32; ++j) u[j] = bf16rne(Tf[g * 32 + j][q_l]);
    short* dst = Qt16 + ((size_t)b * LQ + q0 + q_l) * D_ + g * 32;
#pragma unroll
    for (int k = 0; k < 4; ++k) *(us8*)(dst + k * 8) = *(const us8*)&u[k * 8];
}

// ---------- K1: S[c][q] via MFMA, stored fp16; FUSED col-stats AND row-stats partials.
// All stats on f16-QUANTIZED values (identical to re-reading S16). ----------
__global__ __launch_bounds__(256) void k_S_mfma(const short* __restrict__ Ctw,
                                                const short* __restrict__ Qt16,
                                                const float* __restrict__ s0,
                                                const float* __restrict__ s1,
                                                const float* __restrict__ bias,
                                                const int* __restrict__ Cmask,
                                                const int* __restrict__ Qmask,
                                                _Float16* __restrict__ S16,
                                                float* __restrict__ pm,
                                                float* __restrict__ pl,
                                                float* __restrict__ pmr,
                                                float* __restrict__ plr) {
    int b = blockIdx.y;
    int cT = blockIdx.x >> 2, qT = blockIdx.x & 3;
    int c0 = cT * 128, q0 = qT * 128;
    int t = threadIdx.x, w = t >> 6, l = t & 63;
    int wm_ = w >> 1, wn = w & 1;
    __shared__ short As[128 * 64];
    __shared__ short Bs[128 * 64];
    f32x4 acc[4][4] = {};
    const short* Arow = Ctw + ((size_t)b * LC + c0) * D_;
    const short* Brow = Qt16 + ((size_t)b * LQ + q0) * D_;
    int lr = l >> 3, sl = l & 7;
    for (int kt = 0; kt < 2; ++kt) {
        __syncthreads();
#pragma unroll
        for (int i = 0; i < 4; ++i) {
            int r = w * 32 + i * 8 + lr;
            int g = sl ^ (r & 7);
            gll16(Arow + (size_t)r * D_ + kt * 64 + g * 8, &As[(w * 32 + i * 8) * 64]);
            gll16(Brow + (size_t)r * D_ + kt * 64 + g * 8, &Bs[(w * 32 + i * 8) * 64]);
        }
        __syncthreads();
#pragma unroll
        for (int ks = 0; ks < 2; ++ks) {
            int kg = ks * 4 + (l >> 4);
            bf16x8 af[4], bfr[4];
#pragma unroll
            for (int ms = 0; ms < 4; ++ms) {
                int m = wm_ * 64 + ms * 16 + (l & 15);
                af[ms] = *(const bf16x8*)&As[m * 64 + (kg ^ (m & 7)) * 8];
            }
#pragma unroll
            for (int ns = 0; ns < 4; ++ns) {
                int n = wn * 64 + ns * 16 + (l & 15);
                bfr[ns] = *(const bf16x8*)&Bs[n * 64 + (kg ^ (n & 7)) * 8];
            }
#pragma unroll
            for (int ms = 0; ms < 4; ++ms)
#pragma unroll
                for (int ns = 0; ns < 4; ++ns)
                    acc[ms][ns] = __builtin_amdgcn_mfma_f32_16x16x32_bf16(af[ms], bfr[ns], acc[ms][ns], 0, 0, 0);
        }
    }
    float bv = bias[0];
    // preload s0 + Cmask for this thread's 16 c's
    float s0v[16];
    int cmv[16];
#pragma unroll
    for (int ms = 0; ms < 4; ++ms) {
        int cb = c0 + wm_ * 64 + ms * 16 + (l >> 4) * 4;
        float4 sv = *(const float4*)(s0 + b * LC + cb);
        s0v[ms * 4 + 0] = sv.x; s0v[ms * 4 + 1] = sv.y;
        s0v[ms * 4 + 2] = sv.z; s0v[ms * 4 + 3] = sv.w;
        int4 cv = *(const int4*)(Cmask + b * LC + cb);
        cmv[ms * 4 + 0] = cv.x; cmv[ms * 4 + 1] = cv.y;
        cmv[ms * 4 + 2] = cv.z; cmv[ms * 4 + 3] = cv.w;
    }
    // row-stat online accumulators (over this tile's q's, masked by Qmask)
    float rm_[16], rs_[16];
#pragma unroll
    for (int k = 0; k < 16; ++k) { rm_[k] = NEGINF; rs_[k] = 0.f; }
    // stats LDS overlay on As/Bs (compute done)
    __syncthreads();
    float* Mp = (float*)As;               // floats [0,1056): col partials [8][132]
    float* Lp = (float*)Bs;
    float* Rmf = (float*)As + 2048;       // floats [2048,2304): row partials [2][128]
    float* Rsf = (float*)Bs + 2048;
    int prow = wm_ * 4 + (l >> 4);        // 0..7
#pragma unroll
    for (int ns = 0; ns < 4; ++ns) {
        int qi = wn * 64 + ns * 16 + (l & 15);   // 0..127 within tile
        int q = q0 + qi;
        float s1v = s1[b * LQ + q] + bv;
        int qmn = Qmask[b * LQ + q];
        float vq16[16];
#pragma unroll
        for (int ms = 0; ms < 4; ++ms) {
            int cb = c0 + wm_ * 64 + ms * 16 + (l >> 4) * 4;
#pragma unroll
            for (int r = 0; r < 4; ++r) {
                float vf = acc[ms][ns][r] + s0v[ms * 4 + r] + s1v;
                _Float16 h = (_Float16)vf;
                S16[((size_t)b * LC + cb + r) * LQ + q] = h;
                vq16[ms * 4 + r] = (float)h;
            }
        }
        // col partial for this q (over 16 masked c's)
        float mt = NEGINF;
#pragma unroll
        for (int k = 0; k < 16; ++k) mt = fmaxf(mt, cmv[k] ? vq16[k] : NEGINF);
        float st = 0.f;
#pragma unroll
        for (int k = 0; k < 16; ++k) st += cmv[k] ? __expf(vq16[k] - mt) : 0.f;
        Mp[prow * 132 + qi] = mt;
        Lp[prow * 132 + qi] = st;
        // row online update (garbage while rm_==NEGINF is washed out on first real value)
#pragma unroll
        for (int k = 0; k < 16; ++k) {
            float v = qmn ? vq16[k] : NEGINF;
            float mn = fmaxf(rm_[k], v);
            rs_[k] = rs_[k] * __expf(rm_[k] - mn) + __expf(v - mn);
            rm_[k] = mn;
        }
    }
    // reduce rows across the 16 q-columns (lanes sharing l>>4 hold the same c's)
#pragma unroll
    for (int off = 1; off < 16; off <<= 1) {
#pragma unroll
        for (int k = 0; k < 16; ++k) {
            float m2 = __shfl_xor(rm_[k], off, 64);
            float l2 = __shfl_xor(rs_[k], off, 64);
            float mn = fmaxf(rm_[k], m2);
            rs_[k] = rs_[k] * __expf(rm_[k] - mn) + l2 * __expf(m2 - mn);
            rm_[k] = mn;
        }
    }
    if ((l & 15) == 0) {
#pragma unroll
        for (int ms = 0; ms < 4; ++ms)
#pragma unroll
            for (int r = 0; r < 4; ++r) {
                int cl = wm_ * 64 + ms * 16 + (l >> 4) * 4 + r;
                Rmf[wn * 128 + cl] = rm_[ms * 4 + r];
                Rsf[wn * 128 + cl] = rs_[ms * 4 + r];
            }
    }
    __syncthreads();
    if (t < 128) {
        // col combine (8 prow groups)
        float mm = Mp[t], ll = Lp[t];
#pragma unroll
        for (int g = 1; g < 8; ++g) {
            float m2 = Mp[g * 132 + t], l2 = Lp[g * 132 + t];
            float mn = fmaxf(mm, m2);
            ll = ll * __expf(mm - mn) + l2 * __expf(m2 - mn);
            mm = mn;
        }
        size_t o = ((size_t)cT * B_ + b) * LQ + q0 + t;
        pm[o] = mm; pl[o] = ll;
        // row combine (wn halves); zero-fix all-masked rows
        float rm0 = Rmf[t], rs0 = Rsf[t];
        float rm1 = Rmf[128 + t], rs1 = Rsf[128 + t];
        if (rm0 == NEGINF) rs0 = 0.f;
        if (rm1 == NEGINF) rs1 = 0.f;
        float mn = fmaxf(rm0, rm1);
        float lo = rs0 * __expf(rm0 - mn) + rs1 * __expf(rm1 - mn);
        size_t orow = ((size_t)qT * B_ + b) * LC + c0 + t;
        pmr[orow] = mn; plr[orow] = lo;
    }
}

// ---------- K3: combine partials. Blocks [0,64): cols (16-way). [64,320): rows (4-way). ----------
__global__ void k_comb(const float* __restrict__ pm, const float* __restrict__ pl,
                       const float* __restrict__ pmr, const float* __restrict__ plr,
                       float* __restrict__ colmax, float* __restrict__ colsum,
                       float* __restrict__ rowmax, float* __restrict__ rowsum) {
    int bx = blockIdx.x;
    if (bx < (B_ * LQ) / 256) {
        int idx = bx * 256 + threadIdx.x;       // b*LQ + q
        float m = NEGINF, l = 0.f;
#pragma unroll
        for (int ch = 0; ch < CCH; ++ch) {
            float m2 = pm[(size_t)ch * B_ * LQ + idx];
            float l2 = pl[(size_t)ch * B_ * LQ + idx];
            float mn = fmaxf(m, m2);
            l = l * __expf(m - mn) + l2 * __expf(m2 - mn);
            m = mn;
        }
        colmax[idx] = m; colsum[idx] = l;
    } else {
        int idx = (bx - (B_ * LQ) / 256) * 256 + threadIdx.x;  // b*LC + c
        float m = NEGINF, l = 0.f;
#pragma unroll
        for (int ch = 0; ch < RCH; ++ch) {
            float m2 = pmr[(size_t)ch * B_ * LC + idx];
            float l2 = plr[(size_t)ch * B_ * LC + idx];
            float mn = fmaxf(m, m2);
            l = l * __expf(m - mn) + l2 * __expf(m2 - mn);
            m = mn;
        }
        rowmax[idx] = m; rowsum[idx] = l;
    }
}

// ---------- K5: V2 GEMM + FUSED row-softmax writeback (P1 in place over S16).
// Barrier scheme: loop-top s_barrier (prev LDS reads already consumed);
// mid: sched_barrier pins the 2 P1 stores youngest -> s_waitcnt vmcnt(2) lets them
// stay in flight while guaranteeing gll16/S-loads done + lgkmcnt(0) for Bs. ----------
__global__ __launch_bounds__(256) void k_V2_mfma(const short* __restrict__ Cb16,
                                                 _Float16* __restrict__ S16,
                                                 const int* __restrict__ Cmask,
                                                 const int* __restrict__ Qmask,
                                                 const float* __restrict__ colmax,
                                                 const float* __restrict__ colsum,
                                                 const float* __restrict__ rowmax,
                                                 const float* __restrict__ rowsum,
                                                 short* __restrict__ Wf) {
    int b = blockIdx.y;
    int q0 = blockIdx.x * 64;
    int t = threadIdx.x, w = t >> 6, l = t & 63;
    __shared__ short As[128 * 64];
    __shared__ short Bs[64 * 72];
    f32x4 acc[2][4] = {};
    const short* Arow = Cb16 + (size_t)b * D_ * LC;
    int lr = l >> 3, sl = l & 7;
    float cmx[16];
#pragma unroll
    for (int j2 = 0; j2 < 4; ++j2)
        *(float4*)&cmx[j2 * 4] = *(const float4*)(colmax + b * LQ + q0 + w * 16 + j2 * 4);
    int qmv[16];
#pragma unroll
    for (int j2 = 0; j2 < 4; ++j2)
        *(int4*)&qmv[j2 * 4] = *(const int4*)(Qmask + b * LQ + q0 + w * 16 + j2 * 4);
    _Float16* Sq = S16 + (size_t)b * LC * LQ + q0 + w * 16;
    const int* cmb = Cmask + b * LC;
    const float* rmb = rowmax + b * LC;
    const float* rsb = rowsum + b * LC;

    for (int kt = 0; kt < 32; ++kt) {
        int ck = kt * 64;
        __builtin_amdgcn_s_barrier();        // prev iter's LDS reads all consumed
        __builtin_amdgcn_sched_barrier(0);
#pragma unroll
        for (int i = 0; i < 4; ++i) {
            int r = w * 32 + i * 8 + lr;
            int g = sl ^ (r & 7);
            gll16(Arow + (size_t)r * LC + ck + g * 8, &As[(w * 32 + i * 8) * 64]);
        }
        {
            int c = ck + l;
            float cmf = (float)cmb[c];
            float rm = rmb[c];
            float ri = 1.0f / rsb[c];
            _Float16* sp = Sq + (size_t)c * LQ;
            f16x8 v0 = *(const f16x8*)sp;
            f16x8 v1 = *(const f16x8*)(sp + 8);
            // (a) col-softmax exp -> Bs (B operand, bf16)
#pragma unroll
            for (int j = 0; j < 8; ++j)
                Bs[(w * 16 + j) * 72 + l] = (short)bf16rne(cmf * __expf((float)v0[j] - cmx[j]));
#pragma unroll
            for (int j = 0; j < 8; ++j)
                Bs[(w * 16 + 8 + j) * 72 + l] = (short)bf16rne(cmf * __expf((float)v1[j] - cmx[8 + j]));
            // (b) row-softmax -> P1 bf16, in place
            unsigned short p0[8], p1r[8];
#pragma unroll
            for (int j = 0; j < 8; ++j)
                p0[j] = qmv[j] ? bf16rne(__expf((float)v0[j] - rm) * ri) : (unsigned short)0;
#pragma unroll
            for (int j = 0; j < 8; ++j)
                p1r[j] = qmv[8 + j] ? bf16rne(__expf((float)v1[j] - rm) * ri) : (unsigned short)0;
            __builtin_amdgcn_sched_barrier(0);   // pin the stores as the youngest vmem ops
            *(us8*)sp = *(const us8*)&p0[0];
            *(us8*)(sp + 8) = *(const us8*)&p1r[0];
        }
        asm volatile("s_waitcnt vmcnt(2) lgkmcnt(0)" ::: "memory");  // stores may fly
        __builtin_amdgcn_s_barrier();
        __builtin_amdgcn_sched_barrier(0);
#pragma unroll
        for (int ks = 0; ks < 2; ++ks) {
            int kg = ks * 4 + (l >> 4);
            bf16x8 af[2], bfr[4];
#pragma unroll
            for (int ms = 0; ms < 2; ++ms) {
                int m = w * 32 + ms * 16 + (l & 15);
                af[ms] = *(const bf16x8*)&As[m * 64 + (kg ^ (m & 7)) * 8];
            }
#pragma unroll
            for (int ns = 0; ns < 4; ++ns) {
                int n = ns * 16 + (l & 15);
                bfr[ns] = *(const bf16x8*)&Bs[n * 72 + kg * 8];
            }
#pragma unroll
            for (int ms = 0; ms < 2; ++ms)
#pragma unroll
                for (int ns = 0; ns < 4; ++ns)
                    acc[ms][ns] = __builtin_amdgcn_mfma_f32_16x16x32_bf16(af[ms], bfr[ns], acc[ms][ns], 0, 0, 0);
        }
    }
#pragma unroll
    for (int ms = 0; ms < 2; ++ms)
#pragma unroll
        for (int ns = 0; ns < 4; ++ns) {
            int q = q0 + ns * 16 + (l & 15);
            float csi = 1.0f / colsum[b * LQ + q];
#pragma unroll
            for (int r = 0; r < 4; ++r) {
                int dd = w * 32 + ms * 16 + (l >> 4) * 4 + r;
                Wf[((size_t)b * 256 + 128 + dd) * LQ + q] = (short)bf16rne(acc[ms][ns][r] * csi);
            }
        }
}

// ---------- K6: OUT^T GEMM (round-4 proven form): merged 256n x 128c tile,
// full double-buffered LDS, counted vmcnt(6), raw s_barrier. ----------
__global__ __launch_bounds__(512) void k_out_mfma(const short* __restrict__ P1,
                                                  const short* __restrict__ Wf,
                                                  const float* __restrict__ C,
                                                  float* __restrict__ out) {
    int b = blockIdx.y;
    int c0 = blockIdx.x * 128;
    int t = threadIdx.x, w = t >> 6, l = t & 63;
    int wn = w & 3, wc = w >> 2;            // wave tile: n = wn*64.., c = wc*64..
    __shared__ short As[2 * 256 * 64];       // Wf rows (n), 2 x 32 KB
    __shared__ short Bs[2 * 128 * 64];       // P1 rows (c), 2 x 16 KB  -> 96 KB total
    f32x4 acc[4][4] = {};
    const short* Arow = Wf + (size_t)b * 256 * LQ;
    const short* Brow = P1 + ((size_t)b * LC + c0) * LQ;
    int lr = l >> 3, sl = l & 7;
    int g = sl ^ lr;                         // staging swizzle (row&7 == lr)

#define STAGE(p, kt)                                                              \
    {                                                                             \
        short* Ad = As + (p) * (256 * 64);                                        \
        short* Bd = Bs + (p) * (128 * 64);                                        \
        _Pragma("unroll")                                                         \
        for (int i = 0; i < 4; ++i) {                                             \
            int r = w * 32 + i * 8 + lr;                                          \
            gll16(Arow + (size_t)r * LQ + (kt) * 64 + g * 8,                      \
                  &Ad[(w * 32 + i * 8) * 64]);                                    \
        }                                                                         \
        _Pragma("unroll")                                                         \
        for (int i = 0; i < 2; ++i) {                                             \
            int r = w * 16 + i * 8 + lr;                                          \
            gll16(Brow + (size_t)r * LQ + (kt) * 64 + g * 8,                      \
                  &Bd[(w * 16 + i * 8) * 64]);                                    \
        }                                                                         \
    }

    STAGE(0, 0);
    int cur = 0;
    for (int kt = 0; kt < 8; ++kt) {
        if (kt < 7) {
            STAGE(cur ^ 1, kt + 1);
            asm volatile("s_waitcnt vmcnt(6)" ::: "memory");  // cur's 6 done, new 6 in flight
        } else {
            asm volatile("s_waitcnt vmcnt(0)" ::: "memory");
        }
        __builtin_amdgcn_s_barrier();
        __builtin_amdgcn_sched_barrier(0);
        const short* Ac = As + cur * (256 * 64);
        const short* Bc = Bs + cur * (128 * 64);
#pragma unroll
        for (int ks = 0; ks < 2; ++ks) {
            int kg = ks * 4 + (l >> 4);
            bf16x8 af[4], bfr[4];
#pragma unroll
            for (int ms = 0; ms < 4; ++ms) {
                int m = wn * 64 + ms * 16 + (l & 15);
                af[ms] = *(const bf16x8*)&Ac[m * 64 + (kg ^ (m & 7)) * 8];
            }
#pragma unroll
            for (int ns = 0; ns < 4; ++ns) {
                int cc = wc * 64 + ns * 16 + (l & 15);
                bfr[ns] = *(const bf16x8*)&Bc[cc * 64 + (kg ^ (cc & 7)) * 8];
            }
#pragma unroll
            for (int ms = 0; ms < 4; ++ms)
#pragma unroll
                for (int ns = 0; ns < 4; ++ns)
                    acc[ms][ns] = __builtin_amdgcn_mfma_f32_16x16x32_bf16(af[ms], bfr[ns], acc[ms][ns], 0, 0, 0);
        }
        __builtin_amdgcn_s_barrier();       // all waves done reading cur before overwrite
        cur ^= 1;
    }
#undef STAGE
#pragma unroll
    for (int ms = 0; ms < 4; ++ms) {
        int nb = wn * 64 + ms * 16 + (l >> 4) * 4;
#pragma unroll
        for (int ns = 0; ns < 4; ++ns) {
            int c = c0 + wc * 64 + ns * 16 + (l & 15);
#pragma unroll
            for (int r = 0; r < 4; ++r) {
                int n = nb + r;
                float a = acc[ms][ns][r];
                if (n < 128) {
                    float cv = C[((size_t)b * D_ + n) * LC + c];
                    out[((size_t)b * 512 + n) * LC + c] = cv;          // plane 0: Ct
                    out[((size_t)b * 512 + 128 + n) * LC + c] = a;     // plane 1: A
                    out[((size_t)b * 512 + 256 + n) * LC + c] = cv * a;// plane 2: Ct*A
                } else {
                    int dd = n - 128;
                    float cv = C[((size_t)b * D_ + dd) * LC + c];
                    out[((size_t)b * 512 + 384 + dd) * LC + c] = cv * a;// plane 3: Ct*Bm
                }
            }
        }
    }
}

extern "C" void kernel_launch(void* const* d_in, const int* in_sizes, int n_in,
                              void* d_out, int out_size, void* d_ws, size_t ws_size,
                              hipStream_t stream) {
    const float* C     = (const float*)d_in[0];
    const float* Q     = (const float*)d_in[1];
    const int*   Cmask = (const int*)d_in[2];
    const int*   Qmask = (const int*)d_in[3];
    const float* w_c   = (const float*)d_in[4];
    const float* w_q   = (const float*)d_in[5];
    const float* w_mul = (const float*)d_in[6];
    const float* bias  = (const float*)d_in[7];
    float* out = (float*)d_out;

    _Float16* S16 = (_Float16*)d_ws;                      // B*LC*LQ fp16  = 67.1 MB (later: P1 bf16 in place)
    short* Cb16 = (short*)(S16 + (size_t)B_ * LC * LQ);   // B*D*LC bf16   = 16.8 MB
    short* Ctw  = Cb16 + (size_t)B_ * D_ * LC;            // B*LC*D bf16   = 16.8 MB
    short* Qt16 = Ctw + (size_t)B_ * LC * D_;             // B*LQ*D bf16   =  4.2 MB
    short* Wf   = Qt16 + (size_t)B_ * LQ * D_;            // B*256*LQ bf16 =  8.4 MB
    float* s0     = (float*)(Wf + (size_t)B_ * 256 * LQ); // B*LC
    float* s1     = s0 + B_ * LC;                         // B*LQ
    float* colmax = s1 + B_ * LQ;                         // B*LQ
    float* colsum = colmax + B_ * LQ;                     // B*LQ
    float* rowmax = colsum + B_ * LQ;                     // B*LC
    float* rowsum = rowmax + B_ * LC;                     // B*LC
    float* pm     = rowsum + B_ * LC;                     // CCH*B*LQ = 1 MB
    float* pl     = pm + (size_t)CCH * B_ * LQ;           // CCH*B*LQ = 1 MB
    float* pmr    = pl + (size_t)CCH * B_ * LQ;           // RCH*B*LC = 1 MB
    float* plr    = pmr + (size_t)RCH * B_ * LC;          // RCH*B*LC = 1 MB

    hipLaunchKernelGGL(k_dotw, dim3(B_ * LC / 256), dim3(256), 0, stream, C, w_c, s0, LC);
    hipLaunchKernelGGL(k_dotw, dim3(B_ * LQ / 256), dim3(256), 0, stream, Q, w_q, s1, LQ);
    hipLaunchKernelGGL(k_prep_C, dim3(LC / 64, B_), dim3(256), 0, stream, C, w_mul, Ctw, Cb16);
    hipLaunchKernelGGL(k_prep_Q, dim3(LQ / 64, B_), dim3(256), 0, stream, Q, Qt16, Wf);
    // k_S emits S16 + col partials (pm/pl) + row partials (pmr/plr)
    hipLaunchKernelGGL(k_S_mfma, dim3((LC / 128) * (LQ / 128), B_), dim3(256), 0, stream,
                       Ctw, Qt16, s0, s1, bias, Cmask, Qmask, S16, pm, pl, pmr, plr);
    hipLaunchKernelGGL(k_comb, dim3((B_ * LQ + B_ * LC) / 256), dim3(256), 0, stream,
                       pm, pl, pmr, plr, colmax, colsum, rowmax, rowsum);
    // V2 GEMM + fused row-softmax writeback (S16 -> P1 in place, non-draining stores)
    hipLaunchKernelGGL(k_V2_mfma, dim3(LQ / 64, B_), dim3(256), 0, stream,
                       Cb16, S16, Cmask, Qmask, colmax, colsum, rowmax, rowsum, Wf);
    hipLaunchKernelGGL(k_out_mfma, dim3(LC / 128, B_), dim3(512), 0, stream,
                       (const short*)S16, Wf, C, out);
}

// Round 9
// 386.765 us; speedup vs baseline: 1.0929x; 1.0929x over previous
//
#include <hip/hip_runtime.h>

#define B_ 32
#define D_ 128
#define LC 2048
#define LQ 512
#define CCH 16   // col-partials count == LC/128 (one per k_S c-tile)
#define RCH 4    // row-partials count == LQ/128 (one per k_S q-tile)

#define NEGINF (-3.0e38f)

typedef __attribute__((ext_vector_type(8))) short bf16x8;
typedef __attribute__((ext_vector_type(4))) float f32x4;
typedef __attribute__((ext_vector_type(8))) unsigned short us8;
typedef __attribute__((ext_vector_type(8))) _Float16 f16x8;

__device__ __forceinline__ unsigned short bf16rne(float x) {
    unsigned int u = __float_as_uint(x);
    u = (u + 0x7FFFu + ((u >> 16) & 1u)) >> 16;
    return (unsigned short)u;
}

__device__ __forceinline__ void gll16(const void* g, void* l) {
    __builtin_amdgcn_global_load_lds((const __attribute__((address_space(1))) void*)g,
                                     (__attribute__((address_space(3))) void*)l, 16, 0, 0);
}

// ---------- K0: outv[b,x] = sum_d X[b,d,x] * w[d] ----------
__global__ void k_dotw(const float* __restrict__ X, const float* __restrict__ w,
                       float* __restrict__ outv, int L) {
    int idx = blockIdx.x * 256 + threadIdx.x;
    int b = idx / L, x = idx - b * L;
    const float* Xp = X + (size_t)b * D_ * L + x;
    float acc = 0.f;
#pragma unroll 8
    for (int dd = 0; dd < D_; ++dd) acc += Xp[(size_t)dd * L] * w[dd];
    outv[idx] = acc;
}

// ---------- prep C ----------
__global__ void k_prep_C(const float* __restrict__ C, const float* __restrict__ wmul,
                         short* __restrict__ Ctw, short* __restrict__ Cb16) {
    int b = blockIdx.y, c0 = blockIdx.x * 64;
    __shared__ float Tf[128][65];
    __shared__ float wm[128];
    int t = threadIdx.x;
    if (t < 128) wm[t] = wmul[t];
    const float* Cb = C + (size_t)b * D_ * LC;
#pragma unroll
    for (int i = 0; i < 8; ++i) {
        int idx = t + i * 256;
        int d = idx >> 4, c4 = idx & 15;
        float4 v = *(const float4*)(Cb + (size_t)d * LC + c0 + c4 * 4);
        Tf[d][c4 * 4 + 0] = v.x; Tf[d][c4 * 4 + 1] = v.y;
        Tf[d][c4 * 4 + 2] = v.z; Tf[d][c4 * 4 + 3] = v.w;
        ushort4 cv;
        cv.x = bf16rne(v.x); cv.y = bf16rne(v.y); cv.z = bf16rne(v.z); cv.w = bf16rne(v.w);
        *(ushort4*)(Cb16 + ((size_t)b * D_ + d) * LC + c0 + c4 * 4) = cv;
    }
    __syncthreads();
    int c_l = t & 63, g = t >> 6;
    unsigned short u[32];
#pragma unroll
    for (int j = 0; j < 32; ++j) {
        int d = g * 32 + j;
        u[j] = bf16rne(Tf[d][c_l] * wm[d]);
    }
    short* dst = Ctw + ((size_t)b * LC + c0 + c_l) * D_ + g * 32;
#pragma unroll
    for (int k = 0; k < 4; ++k) *(us8*)(dst + k * 8) = *(const us8*)&u[k * 8];
}

// ---------- prep Q ----------
__global__ void k_prep_Q(const float* __restrict__ Q, short* __restrict__ Qt16,
                         short* __restrict__ Wf) {
    int b = blockIdx.y, q0 = blockIdx.x * 64;
    __shared__ float Tf[128][65];
    int t = threadIdx.x;
    const float* Qb = Q + (size_t)b * D_ * LQ;
#pragma unroll
    for (int i = 0; i < 8; ++i) {
        int idx = t + i * 256;
        int d = idx >> 4, q4 = idx & 15;
        float4 v = *(const float4*)(Qb + (size_t)d * LQ + q0 + q4 * 4);
        Tf[d][q4 * 4 + 0] = v.x; Tf[d][q4 * 4 + 1] = v.y;
        Tf[d][q4 * 4 + 2] = v.z; Tf[d][q4 * 4 + 3] = v.w;
        ushort4 cv;
        cv.x = bf16rne(v.x); cv.y = bf16rne(v.y); cv.z = bf16rne(v.z); cv.w = bf16rne(v.w);
        *(ushort4*)(Wf + ((size_t)b * 256 + d) * LQ + q0 + q4 * 4) = cv;
    }
    __syncthreads();
    int q_l = t & 63, g = t >> 6;
    unsigned short u[32];
#pragma unroll
    for (int j = 0; j < 32; ++j) u[j] = bf16rne(Tf[g * 32 + j][q_l]);
    short* dst = Qt16 + ((size_t)b * LQ + q0 + q_l) * D_ + g * 32;
#pragma unroll
    for (int k = 0; k < 4; ++k) *(us8*)(dst + k * 8) = *(const us8*)&u[k * 8];
}

// ---------- K1: S[c][q] via MFMA, stored fp16; FUSED col-stats (max-shifted) and
// row-SUM partials (zero-shift: softmax is shift-invariant; |S|<~20 so exp() is
// fp32-safe). Row partial = 64 exp + add-only shfl tree (round-8's online version
// cost ~320 exp -> 87us VALU-bound; this is the fix). ----------
__global__ __launch_bounds__(256) void k_S_mfma(const short* __restrict__ Ctw,
                                                const short* __restrict__ Qt16,
                                                const float* __restrict__ s0,
                                                const float* __restrict__ s1,
                                                const float* __restrict__ bias,
                                                const int* __restrict__ Cmask,
                                                const int* __restrict__ Qmask,
                                                _Float16* __restrict__ S16,
                                                float* __restrict__ pm,
                                                float* __restrict__ pl,
                                                float* __restrict__ plr) {
    int b = blockIdx.y;
    int cT = blockIdx.x >> 2, qT = blockIdx.x & 3;
    int c0 = cT * 128, q0 = qT * 128;
    int t = threadIdx.x, w = t >> 6, l = t & 63;
    int wm_ = w >> 1, wn = w & 1;
    __shared__ short As[128 * 64];
    __shared__ short Bs[128 * 64];
    f32x4 acc[4][4] = {};
    const short* Arow = Ctw + ((size_t)b * LC + c0) * D_;
    const short* Brow = Qt16 + ((size_t)b * LQ + q0) * D_;
    int lr = l >> 3, sl = l & 7;
    for (int kt = 0; kt < 2; ++kt) {
        __syncthreads();
#pragma unroll
        for (int i = 0; i < 4; ++i) {
            int r = w * 32 + i * 8 + lr;
            int g = sl ^ (r & 7);
            gll16(Arow + (size_t)r * D_ + kt * 64 + g * 8, &As[(w * 32 + i * 8) * 64]);
            gll16(Brow + (size_t)r * D_ + kt * 64 + g * 8, &Bs[(w * 32 + i * 8) * 64]);
        }
        __syncthreads();
#pragma unroll
        for (int ks = 0; ks < 2; ++ks) {
            int kg = ks * 4 + (l >> 4);
            bf16x8 af[4], bfr[4];
#pragma unroll
            for (int ms = 0; ms < 4; ++ms) {
                int m = wm_ * 64 + ms * 16 + (l & 15);
                af[ms] = *(const bf16x8*)&As[m * 64 + (kg ^ (m & 7)) * 8];
            }
#pragma unroll
            for (int ns = 0; ns < 4; ++ns) {
                int n = wn * 64 + ns * 16 + (l & 15);
                bfr[ns] = *(const bf16x8*)&Bs[n * 64 + (kg ^ (n & 7)) * 8];
            }
#pragma unroll
            for (int ms = 0; ms < 4; ++ms)
#pragma unroll
                for (int ns = 0; ns < 4; ++ns)
                    acc[ms][ns] = __builtin_amdgcn_mfma_f32_16x16x32_bf16(af[ms], bfr[ns], acc[ms][ns], 0, 0, 0);
        }
    }
    float bv = bias[0];
    // preload s0 + Cmask for this thread's 16 c's
    float s0v[16];
    int cmv[16];
#pragma unroll
    for (int ms = 0; ms < 4; ++ms) {
        int cb = c0 + wm_ * 64 + ms * 16 + (l >> 4) * 4;
        float4 sv = *(const float4*)(s0 + b * LC + cb);
        s0v[ms * 4 + 0] = sv.x; s0v[ms * 4 + 1] = sv.y;
        s0v[ms * 4 + 2] = sv.z; s0v[ms * 4 + 3] = sv.w;
        int4 cv = *(const int4*)(Cmask + b * LC + cb);
        cmv[ms * 4 + 0] = cv.x; cmv[ms * 4 + 1] = cv.y;
        cmv[ms * 4 + 2] = cv.z; cmv[ms * 4 + 3] = cv.w;
    }
    // row-sum accumulators, zero-shift
    float rs_[16];
#pragma unroll
    for (int k = 0; k < 16; ++k) rs_[k] = 0.f;
    // stats LDS overlay on As/Bs (compute done)
    __syncthreads();
    float* Mp = (float*)As;               // col-max partials [8][132]
    float* Lp = (float*)Bs;               // col-sum partials [8][132]
    float* Rsf = (float*)As + 2048;       // row-sum halves [2][128]
    int prow = wm_ * 4 + (l >> 4);        // 0..7
#pragma unroll
    for (int ns = 0; ns < 4; ++ns) {
        int qi = wn * 64 + ns * 16 + (l & 15);   // 0..127 within tile
        int q = q0 + qi;
        float s1v = s1[b * LQ + q] + bv;
        int qmn = Qmask[b * LQ + q];
        float vq16[16];
#pragma unroll
        for (int ms = 0; ms < 4; ++ms) {
            int cb = c0 + wm_ * 64 + ms * 16 + (l >> 4) * 4;
#pragma unroll
            for (int r = 0; r < 4; ++r) {
                float vf = acc[ms][ns][r] + s0v[ms * 4 + r] + s1v;
                _Float16 h = (_Float16)vf;
                S16[((size_t)b * LC + cb + r) * LQ + q] = h;
                vq16[ms * 4 + r] = (float)h;
            }
        }
        // col partial for this q (over 16 masked c's), max-shifted
        float mt = NEGINF;
#pragma unroll
        for (int k = 0; k < 16; ++k) mt = fmaxf(mt, cmv[k] ? vq16[k] : NEGINF);
        float st = 0.f;
#pragma unroll
        for (int k = 0; k < 16; ++k) st += cmv[k] ? __expf(vq16[k] - mt) : 0.f;
        Mp[prow * 132 + qi] = mt;
        Lp[prow * 132 + qi] = st;
        // row partial: plain masked exp-sum (zero shift) — 1 exp/elem
#pragma unroll
        for (int k = 0; k < 16; ++k) rs_[k] += qmn ? __expf(vq16[k]) : 0.f;
    }
    // add-only tree over the 16 q-columns (lanes sharing l>>4 hold the same c's)
#pragma unroll
    for (int off = 1; off < 16; off <<= 1)
#pragma unroll
        for (int k = 0; k < 16; ++k) rs_[k] += __shfl_xor(rs_[k], off, 64);
    if ((l & 15) == 0) {
#pragma unroll
        for (int ms = 0; ms < 4; ++ms)
#pragma unroll
            for (int r = 0; r < 4; ++r) {
                int cl = wm_ * 64 + ms * 16 + (l >> 4) * 4 + r;
                Rsf[wn * 128 + cl] = rs_[ms * 4 + r];
            }
    }
    __syncthreads();
    if (t < 128) {
        // col combine (8 prow groups)
        float mm = Mp[t], ll = Lp[t];
#pragma unroll
        for (int g = 1; g < 8; ++g) {
            float m2 = Mp[g * 132 + t], l2 = Lp[g * 132 + t];
            float mn = fmaxf(mm, m2);
            ll = ll * __expf(mm - mn) + l2 * __expf(m2 - mn);
            mm = mn;
        }
        size_t o = ((size_t)cT * B_ + b) * LQ + q0 + t;
        pm[o] = mm; pl[o] = ll;
        // row combine: plain sum of the two wn halves
        size_t orow = ((size_t)qT * B_ + b) * LC + c0 + t;
        plr[orow] = Rsf[t] + Rsf[128 + t];
    }
}

// ---------- K3: combine partials. Blocks [0,64): cols (16-way m/l). [64,320): rows (4-way sum). ----------
__global__ void k_comb(const float* __restrict__ pm, const float* __restrict__ pl,
                       const float* __restrict__ plr,
                       float* __restrict__ colmax, float* __restrict__ colsum,
                       float* __restrict__ rowsum) {
    int bx = blockIdx.x;
    if (bx < (B_ * LQ) / 256) {
        int idx = bx * 256 + threadIdx.x;       // b*LQ + q
        float m = NEGINF, l = 0.f;
#pragma unroll
        for (int ch = 0; ch < CCH; ++ch) {
            float m2 = pm[(size_t)ch * B_ * LQ + idx];
            float l2 = pl[(size_t)ch * B_ * LQ + idx];
            float mn = fmaxf(m, m2);
            l = l * __expf(m - mn) + l2 * __expf(m2 - mn);
            m = mn;
        }
        colmax[idx] = m; colsum[idx] = l;
    } else {
        int idx = (bx - (B_ * LQ) / 256) * 256 + threadIdx.x;  // b*LC + c
        float s = 0.f;
#pragma unroll
        for (int ch = 0; ch < RCH; ++ch) s += plr[(size_t)ch * B_ * LC + idx];
        rowsum[idx] = s;
    }
}

// ---------- K5: V2 GEMM + FUSED row-softmax writeback (P1 in place over S16).
// P1 = qmask * exp(S) / rowsum  (zero-shift, shift-invariant). Non-draining stores:
// sched_barrier pins the 2 P1 stores youngest -> vmcnt(2) lets them fly. ----------
__global__ __launch_bounds__(256) void k_V2_mfma(const short* __restrict__ Cb16,
                                                 _Float16* __restrict__ S16,
                                                 const int* __restrict__ Cmask,
                                                 const int* __restrict__ Qmask,
                                                 const float* __restrict__ colmax,
                                                 const float* __restrict__ colsum,
                                                 const float* __restrict__ rowsum,
                                                 short* __restrict__ Wf) {
    int b = blockIdx.y;
    int q0 = blockIdx.x * 64;
    int t = threadIdx.x, w = t >> 6, l = t & 63;
    __shared__ short As[128 * 64];
    __shared__ short Bs[64 * 72];
    f32x4 acc[2][4] = {};
    const short* Arow = Cb16 + (size_t)b * D_ * LC;
    int lr = l >> 3, sl = l & 7;
    float cmx[16];
#pragma unroll
    for (int j2 = 0; j2 < 4; ++j2)
        *(float4*)&cmx[j2 * 4] = *(const float4*)(colmax + b * LQ + q0 + w * 16 + j2 * 4);
    int qmv[16];
#pragma unroll
    for (int j2 = 0; j2 < 4; ++j2)
        *(int4*)&qmv[j2 * 4] = *(const int4*)(Qmask + b * LQ + q0 + w * 16 + j2 * 4);
    _Float16* Sq = S16 + (size_t)b * LC * LQ + q0 + w * 16;
    const int* cmb = Cmask + b * LC;
    const float* rsb = rowsum + b * LC;

    for (int kt = 0; kt < 32; ++kt) {
        int ck = kt * 64;
        __builtin_amdgcn_s_barrier();        // prev iter's LDS reads all consumed
        __builtin_amdgcn_sched_barrier(0);
#pragma unroll
        for (int i = 0; i < 4; ++i) {
            int r = w * 32 + i * 8 + lr;
            int g = sl ^ (r & 7);
            gll16(Arow + (size_t)r * LC + ck + g * 8, &As[(w * 32 + i * 8) * 64]);
        }
        {
            int c = ck + l;
            float cmf = (float)cmb[c];
            float ri = 1.0f / rsb[c];
            _Float16* sp = Sq + (size_t)c * LQ;
            f16x8 v0 = *(const f16x8*)sp;
            f16x8 v1 = *(const f16x8*)(sp + 8);
            // (a) col-softmax exp -> Bs (B operand, bf16)
#pragma unroll
            for (int j = 0; j < 8; ++j)
                Bs[(w * 16 + j) * 72 + l] = (short)bf16rne(cmf * __expf((float)v0[j] - cmx[j]));
#pragma unroll
            for (int j = 0; j < 8; ++j)
                Bs[(w * 16 + 8 + j) * 72 + l] = (short)bf16rne(cmf * __expf((float)v1[j] - cmx[8 + j]));
            // (b) row-softmax -> P1 bf16, in place (zero-shift)
            unsigned short p0[8], p1r[8];
#pragma unroll
            for (int j = 0; j < 8; ++j)
                p0[j] = qmv[j] ? bf16rne(__expf((float)v0[j]) * ri) : (unsigned short)0;
#pragma unroll
            for (int j = 0; j < 8; ++j)
                p1r[j] = qmv[8 + j] ? bf16rne(__expf((float)v1[j]) * ri) : (unsigned short)0;
            __builtin_amdgcn_sched_barrier(0);   // pin the stores as the youngest vmem ops
            *(us8*)sp = *(const us8*)&p0[0];
            *(us8*)(sp + 8) = *(const us8*)&p1r[0];
        }
        asm volatile("s_waitcnt vmcnt(2) lgkmcnt(0)" ::: "memory");  // stores may fly
        __builtin_amdgcn_s_barrier();
        __builtin_amdgcn_sched_barrier(0);
#pragma unroll
        for (int ks = 0; ks < 2; ++ks) {
            int kg = ks * 4 + (l >> 4);
            bf16x8 af[2], bfr[4];
#pragma unroll
            for (int ms = 0; ms < 2; ++ms) {
                int m = w * 32 + ms * 16 + (l & 15);
                af[ms] = *(const bf16x8*)&As[m * 64 + (kg ^ (m & 7)) * 8];
            }
#pragma unroll
            for (int ns = 0; ns < 4; ++ns) {
                int n = ns * 16 + (l & 15);
                bfr[ns] = *(const bf16x8*)&Bs[n * 72 + kg * 8];
            }
#pragma unroll
            for (int ms = 0; ms < 2; ++ms)
#pragma unroll
                for (int ns = 0; ns < 4; ++ns)
                    acc[ms][ns] = __builtin_amdgcn_mfma_f32_16x16x32_bf16(af[ms], bfr[ns], acc[ms][ns], 0, 0, 0);
        }
    }
#pragma unroll
    for (int ms = 0; ms < 2; ++ms)
#pragma unroll
        for (int ns = 0; ns < 4; ++ns) {
            int q = q0 + ns * 16 + (l & 15);
            float csi = 1.0f / colsum[b * LQ + q];
#pragma unroll
            for (int r = 0; r < 4; ++r) {
                int dd = w * 32 + ms * 16 + (l >> 4) * 4 + r;
                Wf[((size_t)b * 256 + 128 + dd) * LQ + q] = (short)bf16rne(acc[ms][ns][r] * csi);
            }
        }
}

// ---------- K6: OUT^T GEMM (round-4 proven form): merged 256n x 128c tile,
// full double-buffered LDS, counted vmcnt(6), raw s_barrier. ----------
__global__ __launch_bounds__(512) void k_out_mfma(const short* __restrict__ P1,
                                                  const short* __restrict__ Wf,
                                                  const float* __restrict__ C,
                                                  float* __restrict__ out) {
    int b = blockIdx.y;
    int c0 = blockIdx.x * 128;
    int t = threadIdx.x, w = t >> 6, l = t & 63;
    int wn = w & 3, wc = w >> 2;            // wave tile: n = wn*64.., c = wc*64..
    __shared__ short As[2 * 256 * 64];       // Wf rows (n), 2 x 32 KB
    __shared__ short Bs[2 * 128 * 64];       // P1 rows (c), 2 x 16 KB  -> 96 KB total
    f32x4 acc[4][4] = {};
    const short* Arow = Wf + (size_t)b * 256 * LQ;
    const short* Brow = P1 + ((size_t)b * LC + c0) * LQ;
    int lr = l >> 3, sl = l & 7;
    int g = sl ^ lr;                         // staging swizzle (row&7 == lr)

#define STAGE(p, kt)                                                              \
    {                                                                             \
        short* Ad = As + (p) * (256 * 64);                                        \
        short* Bd = Bs + (p) * (128 * 64);                                        \
        _Pragma("unroll")                                                         \
        for (int i = 0; i < 4; ++i) {                                             \
            int r = w * 32 + i * 8 + lr;                                          \
            gll16(Arow + (size_t)r * LQ + (kt) * 64 + g * 8,                      \
                  &Ad[(w * 32 + i * 8) * 64]);                                    \
        }                                                                         \
        _Pragma("unroll")                                                         \
        for (int i = 0; i < 2; ++i) {                                             \
            int r = w * 16 + i * 8 + lr;                                          \
            gll16(Brow + (size_t)r * LQ + (kt) * 64 + g * 8,                      \
                  &Bd[(w * 16 + i * 8) * 64]);                                    \
        }                                                                         \
    }

    STAGE(0, 0);
    int cur = 0;
    for (int kt = 0; kt < 8; ++kt) {
        if (kt < 7) {
            STAGE(cur ^ 1, kt + 1);
            asm volatile("s_waitcnt vmcnt(6)" ::: "memory");  // cur's 6 done, new 6 in flight
        } else {
            asm volatile("s_waitcnt vmcnt(0)" ::: "memory");
        }
        __builtin_amdgcn_s_barrier();
        __builtin_amdgcn_sched_barrier(0);
        const short* Ac = As + cur * (256 * 64);
        const short* Bc = Bs + cur * (128 * 64);
#pragma unroll
        for (int ks = 0; ks < 2; ++ks) {
            int kg = ks * 4 + (l >> 4);
            bf16x8 af[4], bfr[4];
#pragma unroll
            for (int ms = 0; ms < 4; ++ms) {
                int m = wn * 64 + ms * 16 + (l & 15);
                af[ms] = *(const bf16x8*)&Ac[m * 64 + (kg ^ (m & 7)) * 8];
            }
#pragma unroll
            for (int ns = 0; ns < 4; ++ns) {
                int cc = wc * 64 + ns * 16 + (l & 15);
                bfr[ns] = *(const bf16x8*)&Bc[cc * 64 + (kg ^ (cc & 7)) * 8];
            }
#pragma unroll
            for (int ms = 0; ms < 4; ++ms)
#pragma unroll
                for (int ns = 0; ns < 4; ++ns)
                    acc[ms][ns] = __builtin_amdgcn_mfma_f32_16x16x32_bf16(af[ms], bfr[ns], acc[ms][ns], 0, 0, 0);
        }
        __builtin_amdgcn_s_barrier();       // all waves done reading cur before overwrite
        cur ^= 1;
    }
#undef STAGE
#pragma unroll
    for (int ms = 0; ms < 4; ++ms) {
        int nb = wn * 64 + ms * 16 + (l >> 4) * 4;
#pragma unroll
        for (int ns = 0; ns < 4; ++ns) {
            int c = c0 + wc * 64 + ns * 16 + (l & 15);
#pragma unroll
            for (int r = 0; r < 4; ++r) {
                int n = nb + r;
                float a = acc[ms][ns][r];
                if (n < 128) {
                    float cv = C[((size_t)b * D_ + n) * LC + c];
                    out[((size_t)b * 512 + n) * LC + c] = cv;          // plane 0: Ct
                    out[((size_t)b * 512 + 128 + n) * LC + c] = a;     // plane 1: A
                    out[((size_t)b * 512 + 256 + n) * LC + c] = cv * a;// plane 2: Ct*A
                } else {
                    int dd = n - 128;
                    float cv = C[((size_t)b * D_ + dd) * LC + c];
                    out[((size_t)b * 512 + 384 + dd) * LC + c] = cv * a;// plane 3: Ct*Bm
                }
            }
        }
    }
}

extern "C" void kernel_launch(void* const* d_in, const int* in_sizes, int n_in,
                              void* d_out, int out_size, void* d_ws, size_t ws_size,
                              hipStream_t stream) {
    const float* C     = (const float*)d_in[0];
    const float* Q     = (const float*)d_in[1];
    const int*   Cmask = (const int*)d_in[2];
    const int*   Qmask = (const int*)d_in[3];
    const float* w_c   = (const float*)d_in[4];
    const float* w_q   = (const float*)d_in[5];
    const float* w_mul = (const float*)d_in[6];
    const float* bias  = (const float*)d_in[7];
    float* out = (float*)d_out;

    _Float16* S16 = (_Float16*)d_ws;                      // B*LC*LQ fp16  = 67.1 MB (later: P1 bf16 in place)
    short* Cb16 = (short*)(S16 + (size_t)B_ * LC * LQ);   // B*D*LC bf16   = 16.8 MB
    short* Ctw  = Cb16 + (size_t)B_ * D_ * LC;            // B*LC*D bf16   = 16.8 MB
    short* Qt16 = Ctw + (size_t)B_ * LC * D_;             // B*LQ*D bf16   =  4.2 MB
    short* Wf   = Qt16 + (size_t)B_ * LQ * D_;            // B*256*LQ bf16 =  8.4 MB
    float* s0     = (float*)(Wf + (size_t)B_ * 256 * LQ); // B*LC
    float* s1     = s0 + B_ * LC;                         // B*LQ
    float* colmax = s1 + B_ * LQ;                         // B*LQ
    float* colsum = colmax + B_ * LQ;                     // B*LQ
    float* rowsum = colsum + B_ * LQ;                     // B*LC
    float* pm     = rowsum + B_ * LC;                     // CCH*B*LQ = 1 MB
    float* pl     = pm + (size_t)CCH * B_ * LQ;           // CCH*B*LQ = 1 MB
    float* plr    = pl + (size_t)CCH * B_ * LQ;           // RCH*B*LC = 1 MB

    hipLaunchKernelGGL(k_dotw, dim3(B_ * LC / 256), dim3(256), 0, stream, C, w_c, s0, LC);
    hipLaunchKernelGGL(k_dotw, dim3(B_ * LQ / 256), dim3(256), 0, stream, Q, w_q, s1, LQ);
    hipLaunchKernelGGL(k_prep_C, dim3(LC / 64, B_), dim3(256), 0, stream, C, w_mul, Ctw, Cb16);
    hipLaunchKernelGGL(k_prep_Q, dim3(LQ / 64, B_), dim3(256), 0, stream, Q, Qt16, Wf);
    // k_S emits S16 + col partials (pm/pl) + row-sum partials (plr)
    hipLaunchKernelGGL(k_S_mfma, dim3((LC / 128) * (LQ / 128), B_), dim3(256), 0, stream,
                       Ctw, Qt16, s0, s1, bias, Cmask, Qmask, S16, pm, pl, plr);
    hipLaunchKernelGGL(k_comb, dim3((B_ * LQ + B_ * LC) / 256), dim3(256), 0, stream,
                       pm, pl, plr, colmax, colsum, rowsum);
    // V2 GEMM + fused row-softmax writeback (S16 -> P1 in place, non-draining stores)
    hipLaunchKernelGGL(k_V2_mfma, dim3(LQ / 64, B_), dim3(256), 0, stream,
                       Cb16, S16, Cmask, Qmask, colmax, colsum, rowsum, Wf);
    hipLaunchKernelGGL(k_out_mfma, dim3(LC / 128, B_), dim3(512), 0, stream,
                       (const short*)S16, Wf, C, out);
}

// Round 10
// 378.143 us; speedup vs baseline: 1.1179x; 1.0228x over previous
//
#include <hip/hip_runtime.h>

#define B_ 32
#define D_ 128
#define LC 2048
#define LQ 512
#define CCH 16   // col-partials count == LC/128 (one per k_S c-tile)
#define RCH 4    // row-partials count == LQ/128 (one per k_S q-tile)

#define NEGINF (-3.0e38f)

typedef __attribute__((ext_vector_type(8))) short bf16x8;
typedef __attribute__((ext_vector_type(4))) float f32x4;
typedef __attribute__((ext_vector_type(8))) unsigned short us8;
typedef __attribute__((ext_vector_type(8))) _Float16 f16x8;

__device__ __forceinline__ unsigned short bf16rne(float x) {
    unsigned int u = __float_as_uint(x);
    u = (u + 0x7FFFu + ((u >> 16) & 1u)) >> 16;
    return (unsigned short)u;
}

__device__ __forceinline__ void gll16(const void* g, void* l) {
    __builtin_amdgcn_global_load_lds((const __attribute__((address_space(1))) void*)g,
                                     (__attribute__((address_space(3))) void*)l, 16, 0, 0);
}

// ---------- K0: outv[b,x] = sum_d X[b,d,x] * w[d] ----------
__global__ void k_dotw(const float* __restrict__ X, const float* __restrict__ w,
                       float* __restrict__ outv, int L) {
    int idx = blockIdx.x * 256 + threadIdx.x;
    int b = idx / L, x = idx - b * L;
    const float* Xp = X + (size_t)b * D_ * L + x;
    float acc = 0.f;
#pragma unroll 8
    for (int dd = 0; dd < D_; ++dd) acc += Xp[(size_t)dd * L] * w[dd];
    outv[idx] = acc;
}

// ---------- prep C ----------
__global__ void k_prep_C(const float* __restrict__ C, const float* __restrict__ wmul,
                         short* __restrict__ Ctw, short* __restrict__ Cb16) {
    int b = blockIdx.y, c0 = blockIdx.x * 64;
    __shared__ float Tf[128][65];
    __shared__ float wm[128];
    int t = threadIdx.x;
    if (t < 128) wm[t] = wmul[t];
    const float* Cb = C + (size_t)b * D_ * LC;
#pragma unroll
    for (int i = 0; i < 8; ++i) {
        int idx = t + i * 256;
        int d = idx >> 4, c4 = idx & 15;
        float4 v = *(const float4*)(Cb + (size_t)d * LC + c0 + c4 * 4);
        Tf[d][c4 * 4 + 0] = v.x; Tf[d][c4 * 4 + 1] = v.y;
        Tf[d][c4 * 4 + 2] = v.z; Tf[d][c4 * 4 + 3] = v.w;
        ushort4 cv;
        cv.x = bf16rne(v.x); cv.y = bf16rne(v.y); cv.z = bf16rne(v.z); cv.w = bf16rne(v.w);
        *(ushort4*)(Cb16 + ((size_t)b * D_ + d) * LC + c0 + c4 * 4) = cv;
    }
    __syncthreads();
    int c_l = t & 63, g = t >> 6;
    unsigned short u[32];
#pragma unroll
    for (int j = 0; j < 32; ++j) {
        int d = g * 32 + j;
        u[j] = bf16rne(Tf[d][c_l] * wm[d]);
    }
    short* dst = Ctw + ((size_t)b * LC + c0 + c_l) * D_ + g * 32;
#pragma unroll
    for (int k = 0; k < 4; ++k) *(us8*)(dst + k * 8) = *(const us8*)&u[k * 8];
}

// ---------- prep Q ----------
__global__ void k_prep_Q(const float* __restrict__ Q, short* __restrict__ Qt16,
                         short* __restrict__ Wf) {
    int b = blockIdx.y, q0 = blockIdx.x * 64;
    __shared__ float Tf[128][65];
    int t = threadIdx.x;
    const float* Qb = Q + (size_t)b * D_ * LQ;
#pragma unroll
    for (int i = 0; i < 8; ++i) {
        int idx = t + i * 256;
        int d = idx >> 4, q4 = idx & 15;
        float4 v = *(const float4*)(Qb + (size_t)d * LQ + q0 + q4 * 4);
        Tf[d][q4 * 4 + 0] = v.x; Tf[d][q4 * 4 + 1] = v.y;
        Tf[d][q4 * 4 + 2] = v.z; Tf[d][q4 * 4 + 3] = v.w;
        ushort4 cv;
        cv.x = bf16rne(v.x); cv.y = bf16rne(v.y); cv.z = bf16rne(v.z); cv.w = bf16rne(v.w);
        *(ushort4*)(Wf + ((size_t)b * 256 + d) * LQ + q0 + q4 * 4) = cv;
    }
    __syncthreads();
    int q_l = t & 63, g = t >> 6;
    unsigned short u[32];
#pragma unroll
    for (int j = 0; j < 32; ++j) u[j] = bf16rne(Tf[g * 32 + j][q_l]);
    short* dst = Qt16 + ((size_t)b * LQ + q0 + q_l) * D_ + g * 32;
#pragma unroll
    for (int k = 0; k < 4; ++k) *(us8*)(dst + k * 8) = *(const us8*)&u[k * 8];
}

// ---------- K1: S[c][q] via MFMA, stored fp16; FUSED col-stats (max-shifted) and
// row-SUM partials (zero-shift; |S|<~20 so exp() is fp32-safe). ----------
__global__ __launch_bounds__(256) void k_S_mfma(const short* __restrict__ Ctw,
                                                const short* __restrict__ Qt16,
                                                const float* __restrict__ s0,
                                                const float* __restrict__ s1,
                                                const float* __restrict__ bias,
                                                const int* __restrict__ Cmask,
                                                const int* __restrict__ Qmask,
                                                _Float16* __restrict__ S16,
                                                float* __restrict__ pm,
                                                float* __restrict__ pl,
                                                float* __restrict__ plr) {
    int b = blockIdx.y;
    int cT = blockIdx.x >> 2, qT = blockIdx.x & 3;
    int c0 = cT * 128, q0 = qT * 128;
    int t = threadIdx.x, w = t >> 6, l = t & 63;
    int wm_ = w >> 1, wn = w & 1;
    __shared__ short As[128 * 64];
    __shared__ short Bs[128 * 64];
    f32x4 acc[4][4] = {};
    const short* Arow = Ctw + ((size_t)b * LC + c0) * D_;
    const short* Brow = Qt16 + ((size_t)b * LQ + q0) * D_;
    int lr = l >> 3, sl = l & 7;
    for (int kt = 0; kt < 2; ++kt) {
        __syncthreads();
#pragma unroll
        for (int i = 0; i < 4; ++i) {
            int r = w * 32 + i * 8 + lr;
            int g = sl ^ (r & 7);
            gll16(Arow + (size_t)r * D_ + kt * 64 + g * 8, &As[(w * 32 + i * 8) * 64]);
            gll16(Brow + (size_t)r * D_ + kt * 64 + g * 8, &Bs[(w * 32 + i * 8) * 64]);
        }
        __syncthreads();
#pragma unroll
        for (int ks = 0; ks < 2; ++ks) {
            int kg = ks * 4 + (l >> 4);
            bf16x8 af[4], bfr[4];
#pragma unroll
            for (int ms = 0; ms < 4; ++ms) {
                int m = wm_ * 64 + ms * 16 + (l & 15);
                af[ms] = *(const bf16x8*)&As[m * 64 + (kg ^ (m & 7)) * 8];
            }
#pragma unroll
            for (int ns = 0; ns < 4; ++ns) {
                int n = wn * 64 + ns * 16 + (l & 15);
                bfr[ns] = *(const bf16x8*)&Bs[n * 64 + (kg ^ (n & 7)) * 8];
            }
#pragma unroll
            for (int ms = 0; ms < 4; ++ms)
#pragma unroll
                for (int ns = 0; ns < 4; ++ns)
                    acc[ms][ns] = __builtin_amdgcn_mfma_f32_16x16x32_bf16(af[ms], bfr[ns], acc[ms][ns], 0, 0, 0);
        }
    }
    float bv = bias[0];
    float s0v[16];
    int cmv[16];
#pragma unroll
    for (int ms = 0; ms < 4; ++ms) {
        int cb = c0 + wm_ * 64 + ms * 16 + (l >> 4) * 4;
        float4 sv = *(const float4*)(s0 + b * LC + cb);
        s0v[ms * 4 + 0] = sv.x; s0v[ms * 4 + 1] = sv.y;
        s0v[ms * 4 + 2] = sv.z; s0v[ms * 4 + 3] = sv.w;
        int4 cv = *(const int4*)(Cmask + b * LC + cb);
        cmv[ms * 4 + 0] = cv.x; cmv[ms * 4 + 1] = cv.y;
        cmv[ms * 4 + 2] = cv.z; cmv[ms * 4 + 3] = cv.w;
    }
    float rs_[16];
#pragma unroll
    for (int k = 0; k < 16; ++k) rs_[k] = 0.f;
    __syncthreads();
    float* Mp = (float*)As;               // col-max partials [8][132]
    float* Lp = (float*)Bs;               // col-sum partials [8][132]
    float* Rsf = (float*)As + 2048;       // row-sum halves [2][128]
    int prow = wm_ * 4 + (l >> 4);        // 0..7
#pragma unroll
    for (int ns = 0; ns < 4; ++ns) {
        int qi = wn * 64 + ns * 16 + (l & 15);   // 0..127 within tile
        int q = q0 + qi;
        float s1v = s1[b * LQ + q] + bv;
        int qmn = Qmask[b * LQ + q];
        float vq16[16];
#pragma unroll
        for (int ms = 0; ms < 4; ++ms) {
            int cb = c0 + wm_ * 64 + ms * 16 + (l >> 4) * 4;
#pragma unroll
            for (int r = 0; r < 4; ++r) {
                float vf = acc[ms][ns][r] + s0v[ms * 4 + r] + s1v;
                _Float16 h = (_Float16)vf;
                S16[((size_t)b * LC + cb + r) * LQ + q] = h;
                vq16[ms * 4 + r] = (float)h;
            }
        }
        float mt = NEGINF;
#pragma unroll
        for (int k = 0; k < 16; ++k) mt = fmaxf(mt, cmv[k] ? vq16[k] : NEGINF);
        float st = 0.f;
#pragma unroll
        for (int k = 0; k < 16; ++k) st += cmv[k] ? __expf(vq16[k] - mt) : 0.f;
        Mp[prow * 132 + qi] = mt;
        Lp[prow * 132 + qi] = st;
#pragma unroll
        for (int k = 0; k < 16; ++k) rs_[k] += qmn ? __expf(vq16[k]) : 0.f;
    }
#pragma unroll
    for (int off = 1; off < 16; off <<= 1)
#pragma unroll
        for (int k = 0; k < 16; ++k) rs_[k] += __shfl_xor(rs_[k], off, 64);
    if ((l & 15) == 0) {
#pragma unroll
        for (int ms = 0; ms < 4; ++ms)
#pragma unroll
            for (int r = 0; r < 4; ++r) {
                int cl = wm_ * 64 + ms * 16 + (l >> 4) * 4 + r;
                Rsf[wn * 128 + cl] = rs_[ms * 4 + r];
            }
    }
    __syncthreads();
    if (t < 128) {
        float mm = Mp[t], ll = Lp[t];
#pragma unroll
        for (int g = 1; g < 8; ++g) {
            float m2 = Mp[g * 132 + t], l2 = Lp[g * 132 + t];
            float mn = fmaxf(mm, m2);
            ll = ll * __expf(mm - mn) + l2 * __expf(m2 - mn);
            mm = mn;
        }
        size_t o = ((size_t)cT * B_ + b) * LQ + q0 + t;
        pm[o] = mm; pl[o] = ll;
        size_t orow = ((size_t)qT * B_ + b) * LC + c0 + t;
        plr[orow] = Rsf[t] + Rsf[128 + t];
    }
}

// ---------- K3: combine partials ----------
__global__ void k_comb(const float* __restrict__ pm, const float* __restrict__ pl,
                       const float* __restrict__ plr,
                       float* __restrict__ colmax, float* __restrict__ colsum,
                       float* __restrict__ rowsum) {
    int bx = blockIdx.x;
    if (bx < (B_ * LQ) / 256) {
        int idx = bx * 256 + threadIdx.x;       // b*LQ + q
        float m = NEGINF, l = 0.f;
#pragma unroll
        for (int ch = 0; ch < CCH; ++ch) {
            float m2 = pm[(size_t)ch * B_ * LQ + idx];
            float l2 = pl[(size_t)ch * B_ * LQ + idx];
            float mn = fmaxf(m, m2);
            l = l * __expf(m - mn) + l2 * __expf(m2 - mn);
            m = mn;
        }
        colmax[idx] = m; colsum[idx] = l;
    } else {
        int idx = (bx - (B_ * LQ) / 256) * 256 + threadIdx.x;  // b*LC + c
        float s = 0.f;
#pragma unroll
        for (int ch = 0; ch < RCH; ++ch) s += plr[(size_t)ch * B_ * LC + idx];
        rowsum[idx] = s;
    }
}

// ---------- K5: V2 GEMM (no P1 writeback any more — k_out computes row-softmax
// on the fly). Reads raw S once per kt for the col-exp B operand. ----------
__global__ __launch_bounds__(256) void k_V2_mfma(const short* __restrict__ Cb16,
                                                 const _Float16* __restrict__ S16,
                                                 const int* __restrict__ Cmask,
                                                 const float* __restrict__ colmax,
                                                 const float* __restrict__ colsum,
                                                 short* __restrict__ Wf) {
    int b = blockIdx.y;
    int q0 = blockIdx.x * 64;
    int t = threadIdx.x, w = t >> 6, l = t & 63;
    __shared__ short As[128 * 64];
    __shared__ short Bs[64 * 72];
    f32x4 acc[2][4] = {};
    const short* Arow = Cb16 + (size_t)b * D_ * LC;
    int lr = l >> 3, sl = l & 7;
    float cmx[16];
#pragma unroll
    for (int j2 = 0; j2 < 4; ++j2)
        *(float4*)&cmx[j2 * 4] = *(const float4*)(colmax + b * LQ + q0 + w * 16 + j2 * 4);
    const _Float16* Sq = S16 + (size_t)b * LC * LQ + q0 + w * 16;
    const int* cmb = Cmask + b * LC;

    for (int kt = 0; kt < 32; ++kt) {
        int ck = kt * 64;
        __builtin_amdgcn_s_barrier();        // prev iter's LDS reads all consumed
        __builtin_amdgcn_sched_barrier(0);
#pragma unroll
        for (int i = 0; i < 4; ++i) {
            int r = w * 32 + i * 8 + lr;
            int g = sl ^ (r & 7);
            gll16(Arow + (size_t)r * LC + ck + g * 8, &As[(w * 32 + i * 8) * 64]);
        }
        {
            int c = ck + l;
            float cmf = (float)cmb[c];
            const _Float16* sp = Sq + (size_t)c * LQ;
            f16x8 v0 = *(const f16x8*)sp;
            f16x8 v1 = *(const f16x8*)(sp + 8);
#pragma unroll
            for (int j = 0; j < 8; ++j)
                Bs[(w * 16 + j) * 72 + l] = (short)bf16rne(cmf * __expf((float)v0[j] - cmx[j]));
#pragma unroll
            for (int j = 0; j < 8; ++j)
                Bs[(w * 16 + 8 + j) * 72 + l] = (short)bf16rne(cmf * __expf((float)v1[j] - cmx[8 + j]));
        }
        asm volatile("s_waitcnt vmcnt(0) lgkmcnt(0)" ::: "memory");
        __builtin_amdgcn_s_barrier();
        __builtin_amdgcn_sched_barrier(0);
#pragma unroll
        for (int ks = 0; ks < 2; ++ks) {
            int kg = ks * 4 + (l >> 4);
            bf16x8 af[2], bfr[4];
#pragma unroll
            for (int ms = 0; ms < 2; ++ms) {
                int m = w * 32 + ms * 16 + (l & 15);
                af[ms] = *(const bf16x8*)&As[m * 64 + (kg ^ (m & 7)) * 8];
            }
#pragma unroll
            for (int ns = 0; ns < 4; ++ns) {
                int n = ns * 16 + (l & 15);
                bfr[ns] = *(const bf16x8*)&Bs[n * 72 + kg * 8];
            }
#pragma unroll
            for (int ms = 0; ms < 2; ++ms)
#pragma unroll
                for (int ns = 0; ns < 4; ++ns)
                    acc[ms][ns] = __builtin_amdgcn_mfma_f32_16x16x32_bf16(af[ms], bfr[ns], acc[ms][ns], 0, 0, 0);
        }
    }
#pragma unroll
    for (int ms = 0; ms < 2; ++ms)
#pragma unroll
        for (int ns = 0; ns < 4; ++ns) {
            int q = q0 + ns * 16 + (l & 15);
            float csi = 1.0f / colsum[b * LQ + q];
#pragma unroll
            for (int r = 0; r < 4; ++r) {
                int dd = w * 32 + ms * 16 + (l >> 4) * 4 + r;
                Wf[((size_t)b * 256 + 128 + dd) * LQ + q] = (short)bf16rne(acc[ms][ns][r] * csi);
            }
        }
}

// ---------- K6: OUT^T GEMM. A(Wf) via gll16 double-buffer; B = row-softmax P1
// computed ON THE FLY from raw S16 (reg-staged: load f16 -> exp*ri*qmask -> bf16
// -> ds_write, same XOR-swizzled layout as before). vmcnt ladder: per tile
// outstanding = [B_regs(2), A_gll16(4)]; wait vmcnt(6) keeps next tile in flight. ----------
__global__ __launch_bounds__(512) void k_out_mfma(const _Float16* __restrict__ S16,
                                                  const short* __restrict__ Wf,
                                                  const float* __restrict__ C,
                                                  const int* __restrict__ Qmask,
                                                  const float* __restrict__ rowsum,
                                                  float* __restrict__ out) {
    int b = blockIdx.y;
    int c0 = blockIdx.x * 128;
    int t = threadIdx.x, w = t >> 6, l = t & 63;
    int wn = w & 3, wc = w >> 2;            // wave tile: n = wn*64.., c = wc*64..
    __shared__ short As[2 * 256 * 64];       // Wf rows (n), 2 x 32 KB
    __shared__ short Bs[2 * 128 * 64];       // P1 rows (c), 2 x 16 KB
    __shared__ float Qm[LQ];                 // qmask as float, 2 KB  -> 98 KB total
    f32x4 acc[4][4] = {};
    const short* Arow = Wf + (size_t)b * 256 * LQ;
    const _Float16* Brow = S16 + ((size_t)b * LC + c0) * LQ;
    int lr = l >> 3, sl = l & 7;
    int g = sl ^ lr;                         // staging swizzle (row&7 == lr)
    // B thread-fixed rows + their 1/rowsum (constant across kt)
    int r0 = w * 16 + lr, r1 = r0 + 8;
    float ri0 = 1.0f / rowsum[b * LC + c0 + r0];
    float ri1 = 1.0f / rowsum[b * LC + c0 + r1];
    Qm[t] = (float)Qmask[b * LQ + t];        // 512 threads == LQ
    __syncthreads();

#define STAGE_A(p, kt)                                                            \
    {                                                                             \
        short* Ad = As + (p) * (256 * 64);                                        \
        _Pragma("unroll")                                                         \
        for (int i = 0; i < 4; ++i) {                                             \
            int r = w * 32 + i * 8 + lr;                                          \
            gll16(Arow + (size_t)r * LQ + (kt) * 64 + g * 8,                      \
                  &Ad[(w * 32 + i * 8) * 64]);                                    \
        }                                                                         \
    }
#define LOAD_B(v0_, v1_, kt)                                                      \
    v0_ = *(const f16x8*)(Brow + (size_t)r0 * LQ + (kt) * 64 + g * 8);            \
    v1_ = *(const f16x8*)(Brow + (size_t)r1 * LQ + (kt) * 64 + g * 8);

    f16x8 bA0, bA1, bB0, bB1;                // two tiles of B regs in flight
    LOAD_B(bA0, bA1, 0);
    STAGE_A(0, 0);
    LOAD_B(bB0, bB1, 1);
    STAGE_A(1, 1);
    __builtin_amdgcn_sched_barrier(0);
    int cur = 0;
    for (int kt = 0; kt < 8; ++kt) {
        if (kt < 7) asm volatile("s_waitcnt vmcnt(6)" ::: "memory");  // this tile's B+A done
        else        asm volatile("s_waitcnt vmcnt(0)" ::: "memory");
        // build P1 tile in LDS from regs: p = qm ? exp(S)*ri : 0
        {
            f16x8 v0 = (kt & 1) ? bB0 : bA0;
            f16x8 v1 = (kt & 1) ? bB1 : bA1;
            float qm[8];
#pragma unroll
            for (int j = 0; j < 8; ++j) qm[j] = Qm[kt * 64 + g * 8 + j];
            unsigned short p0[8], p1[8];
#pragma unroll
            for (int j = 0; j < 8; ++j)
                p0[j] = (qm[j] != 0.f) ? bf16rne(__expf((float)v0[j]) * ri0) : (unsigned short)0;
#pragma unroll
            for (int j = 0; j < 8; ++j)
                p1[j] = (qm[j] != 0.f) ? bf16rne(__expf((float)v1[j]) * ri1) : (unsigned short)0;
            short* Bd = Bs + cur * (128 * 64);
            *(us8*)&Bd[r0 * 64 + sl * 8] = *(const us8*)&p0[0];
            *(us8*)&Bd[r1 * 64 + sl * 8] = *(const us8*)&p1[0];
        }
        asm volatile("s_waitcnt lgkmcnt(0)" ::: "memory");
        __builtin_amdgcn_s_barrier();
        __builtin_amdgcn_sched_barrier(0);
        const short* Ac = As + cur * (256 * 64);
        const short* Bc = Bs + cur * (128 * 64);
#pragma unroll
        for (int ks = 0; ks < 2; ++ks) {
            int kg = ks * 4 + (l >> 4);
            bf16x8 af[4], bfr[4];
#pragma unroll
            for (int ms = 0; ms < 4; ++ms) {
                int m = wn * 64 + ms * 16 + (l & 15);
                af[ms] = *(const bf16x8*)&Ac[m * 64 + (kg ^ (m & 7)) * 8];
            }
#pragma unroll
            for (int ns = 0; ns < 4; ++ns) {
                int cc = wc * 64 + ns * 16 + (l & 15);
                bfr[ns] = *(const bf16x8*)&Bc[cc * 64 + (kg ^ (cc & 7)) * 8];
            }
#pragma unroll
            for (int ms = 0; ms < 4; ++ms)
#pragma unroll
                for (int ns = 0; ns < 4; ++ns)
                    acc[ms][ns] = __builtin_amdgcn_mfma_f32_16x16x32_bf16(af[ms], bfr[ns], acc[ms][ns], 0, 0, 0);
        }
        __builtin_amdgcn_s_barrier();        // all waves done reading cur
        __builtin_amdgcn_sched_barrier(0);
        if (kt < 6) {
            if (kt & 1) { LOAD_B(bB0, bB1, kt + 2); }
            else        { LOAD_B(bA0, bA1, kt + 2); }
            STAGE_A(cur, kt + 2);
        }
        cur ^= 1;
    }
#undef STAGE_A
#undef LOAD_B
#pragma unroll
    for (int ms = 0; ms < 4; ++ms) {
        int nb = wn * 64 + ms * 16 + (l >> 4) * 4;
#pragma unroll
        for (int ns = 0; ns < 4; ++ns) {
            int c = c0 + wc * 64 + ns * 16 + (l & 15);
#pragma unroll
            for (int r = 0; r < 4; ++r) {
                int n = nb + r;
                float a = acc[ms][ns][r];
                if (n < 128) {
                    float cv = C[((size_t)b * D_ + n) * LC + c];
                    out[((size_t)b * 512 + n) * LC + c] = cv;          // plane 0: Ct
                    out[((size_t)b * 512 + 128 + n) * LC + c] = a;     // plane 1: A
                    out[((size_t)b * 512 + 256 + n) * LC + c] = cv * a;// plane 2: Ct*A
                } else {
                    int dd = n - 128;
                    float cv = C[((size_t)b * D_ + dd) * LC + c];
                    out[((size_t)b * 512 + 384 + dd) * LC + c] = cv * a;// plane 3: Ct*Bm
                }
            }
        }
    }
}

extern "C" void kernel_launch(void* const* d_in, const int* in_sizes, int n_in,
                              void* d_out, int out_size, void* d_ws, size_t ws_size,
                              hipStream_t stream) {
    const float* C     = (const float*)d_in[0];
    const float* Q     = (const float*)d_in[1];
    const int*   Cmask = (const int*)d_in[2];
    const int*   Qmask = (const int*)d_in[3];
    const float* w_c   = (const float*)d_in[4];
    const float* w_q   = (const float*)d_in[5];
    const float* w_mul = (const float*)d_in[6];
    const float* bias  = (const float*)d_in[7];
    float* out = (float*)d_out;

    _Float16* S16 = (_Float16*)d_ws;                      // B*LC*LQ fp16  = 67.1 MB (stays RAW now)
    short* Cb16 = (short*)(S16 + (size_t)B_ * LC * LQ);   // B*D*LC bf16   = 16.8 MB
    short* Ctw  = Cb16 + (size_t)B_ * D_ * LC;            // B*LC*D bf16   = 16.8 MB
    short* Qt16 = Ctw + (size_t)B_ * LC * D_;             // B*LQ*D bf16   =  4.2 MB
    short* Wf   = Qt16 + (size_t)B_ * LQ * D_;            // B*256*LQ bf16 =  8.4 MB
    float* s0     = (float*)(Wf + (size_t)B_ * 256 * LQ); // B*LC
    float* s1     = s0 + B_ * LC;                         // B*LQ
    float* colmax = s1 + B_ * LQ;                         // B*LQ
    float* colsum = colmax + B_ * LQ;                     // B*LQ
    float* rowsum = colsum + B_ * LQ;                     // B*LC
    float* pm     = rowsum + B_ * LC;                     // CCH*B*LQ = 1 MB
    float* pl     = pm + (size_t)CCH * B_ * LQ;           // CCH*B*LQ = 1 MB
    float* plr    = pl + (size_t)CCH * B_ * LQ;           // RCH*B*LC = 1 MB

    hipLaunchKernelGGL(k_dotw, dim3(B_ * LC / 256), dim3(256), 0, stream, C, w_c, s0, LC);
    hipLaunchKernelGGL(k_dotw, dim3(B_ * LQ / 256), dim3(256), 0, stream, Q, w_q, s1, LQ);
    hipLaunchKernelGGL(k_prep_C, dim3(LC / 64, B_), dim3(256), 0, stream, C, w_mul, Ctw, Cb16);
    hipLaunchKernelGGL(k_prep_Q, dim3(LQ / 64, B_), dim3(256), 0, stream, Q, Qt16, Wf);
    // k_S emits S16 + col partials (pm/pl) + row-sum partials (plr)
    hipLaunchKernelGGL(k_S_mfma, dim3((LC / 128) * (LQ / 128), B_), dim3(256), 0, stream,
                       Ctw, Qt16, s0, s1, bias, Cmask, Qmask, S16, pm, pl, plr);
    hipLaunchKernelGGL(k_comb, dim3((B_ * LQ + B_ * LC) / 256), dim3(256), 0, stream,
                       pm, pl, plr, colmax, colsum, rowsum);
    // V2 GEMM (reads raw S; no P1 writeback)
    hipLaunchKernelGGL(k_V2_mfma, dim3(LQ / 64, B_), dim3(256), 0, stream,
                       Cb16, S16, Cmask, colmax, colsum, Wf);
    // OUT GEMM computes row-softmax on the fly from raw S16
    hipLaunchKernelGGL(k_out_mfma, dim3(LC / 128, B_), dim3(512), 0, stream,
                       S16, Wf, C, Qmask, rowsum, out);
}

// Round 11
// 372.405 us; speedup vs baseline: 1.1351x; 1.0154x over previous
//
#include <hip/hip_runtime.h>

#define B_ 32
#define D_ 128
#define LC 2048
#define LQ 512
#define CCH 16   // col-partials count == LC/128 (one per k_S c-tile)
#define RCH 4    // row-partials count == LQ/128 (one per k_S q-tile)

#define NEGINF (-3.0e38f)

typedef __attribute__((ext_vector_type(8))) short bf16x8;
typedef __attribute__((ext_vector_type(4))) float f32x4;
typedef __attribute__((ext_vector_type(8))) unsigned short us8;
typedef __attribute__((ext_vector_type(8))) _Float16 f16x8;

__device__ __forceinline__ unsigned short bf16rne(float x) {
    unsigned int u = __float_as_uint(x);
    u = (u + 0x7FFFu + ((u >> 16) & 1u)) >> 16;
    return (unsigned short)u;
}

__device__ __forceinline__ void gll16(const void* g, void* l) {
    __builtin_amdgcn_global_load_lds((const __attribute__((address_space(1))) void*)g,
                                     (__attribute__((address_space(3))) void*)l, 16, 0, 0);
}

// ---------- K0: outv[b,x] = sum_d X[b,d,x] * w[d] ----------
__global__ void k_dotw(const float* __restrict__ X, const float* __restrict__ w,
                       float* __restrict__ outv, int L) {
    int idx = blockIdx.x * 256 + threadIdx.x;
    int b = idx / L, x = idx - b * L;
    const float* Xp = X + (size_t)b * D_ * L + x;
    float acc = 0.f;
#pragma unroll 8
    for (int dd = 0; dd < D_; ++dd) acc += Xp[(size_t)dd * L] * w[dd];
    outv[idx] = acc;
}

// ---------- prep C ----------
__global__ void k_prep_C(const float* __restrict__ C, const float* __restrict__ wmul,
                         short* __restrict__ Ctw, short* __restrict__ Cb16) {
    int b = blockIdx.y, c0 = blockIdx.x * 64;
    __shared__ float Tf[128][65];
    __shared__ float wm[128];
    int t = threadIdx.x;
    if (t < 128) wm[t] = wmul[t];
    const float* Cb = C + (size_t)b * D_ * LC;
#pragma unroll
    for (int i = 0; i < 8; ++i) {
        int idx = t + i * 256;
        int d = idx >> 4, c4 = idx & 15;
        float4 v = *(const float4*)(Cb + (size_t)d * LC + c0 + c4 * 4);
        Tf[d][c4 * 4 + 0] = v.x; Tf[d][c4 * 4 + 1] = v.y;
        Tf[d][c4 * 4 + 2] = v.z; Tf[d][c4 * 4 + 3] = v.w;
        ushort4 cv;
        cv.x = bf16rne(v.x); cv.y = bf16rne(v.y); cv.z = bf16rne(v.z); cv.w = bf16rne(v.w);
        *(ushort4*)(Cb16 + ((size_t)b * D_ + d) * LC + c0 + c4 * 4) = cv;
    }
    __syncthreads();
    int c_l = t & 63, g = t >> 6;
    unsigned short u[32];
#pragma unroll
    for (int j = 0; j < 32; ++j) {
        int d = g * 32 + j;
        u[j] = bf16rne(Tf[d][c_l] * wm[d]);
    }
    short* dst = Ctw + ((size_t)b * LC + c0 + c_l) * D_ + g * 32;
#pragma unroll
    for (int k = 0; k < 4; ++k) *(us8*)(dst + k * 8) = *(const us8*)&u[k * 8];
}

// ---------- prep Q ----------
__global__ void k_prep_Q(const float* __restrict__ Q, short* __restrict__ Qt16,
                         short* __restrict__ Wf) {
    int b = blockIdx.y, q0 = blockIdx.x * 64;
    __shared__ float Tf[128][65];
    int t = threadIdx.x;
    const float* Qb = Q + (size_t)b * D_ * LQ;
#pragma unroll
    for (int i = 0; i < 8; ++i) {
        int idx = t + i * 256;
        int d = idx >> 4, q4 = idx & 15;
        float4 v = *(const float4*)(Qb + (size_t)d * LQ + q0 + q4 * 4);
        Tf[d][q4 * 4 + 0] = v.x; Tf[d][q4 * 4 + 1] = v.y;
        Tf[d][q4 * 4 + 2] = v.z; Tf[d][q4 * 4 + 3] = v.w;
        ushort4 cv;
        cv.x = bf16rne(v.x); cv.y = bf16rne(v.y); cv.z = bf16rne(v.z); cv.w = bf16rne(v.w);
        *(ushort4*)(Wf + ((size_t)b * 256 + d) * LQ + q0 + q4 * 4) = cv;
    }
    __syncthreads();
    int q_l = t & 63, g = t >> 6;
    unsigned short u[32];
#pragma unroll
    for (int j = 0; j < 32; ++j) u[j] = bf16rne(Tf[g * 32 + j][q_l]);
    short* dst = Qt16 + ((size_t)b * LQ + q0 + q_l) * D_ + g * 32;
#pragma unroll
    for (int k = 0; k < 4; ++k) *(us8*)(dst + k * 8) = *(const us8*)&u[k * 8];
}

// ---------- K1: S[c][q] via MFMA, stored fp16; FUSED col-stats (max-shifted) and
// row-SUM partials (zero-shift; |S|<~20 so exp() is fp32-safe). ----------
__global__ __launch_bounds__(256) void k_S_mfma(const short* __restrict__ Ctw,
                                                const short* __restrict__ Qt16,
                                                const float* __restrict__ s0,
                                                const float* __restrict__ s1,
                                                const float* __restrict__ bias,
                                                const int* __restrict__ Cmask,
                                                const int* __restrict__ Qmask,
                                                _Float16* __restrict__ S16,
                                                float* __restrict__ pm,
                                                float* __restrict__ pl,
                                                float* __restrict__ plr) {
    int b = blockIdx.y;
    int cT = blockIdx.x >> 2, qT = blockIdx.x & 3;
    int c0 = cT * 128, q0 = qT * 128;
    int t = threadIdx.x, w = t >> 6, l = t & 63;
    int wm_ = w >> 1, wn = w & 1;
    __shared__ short As[128 * 64];
    __shared__ short Bs[128 * 64];
    f32x4 acc[4][4] = {};
    const short* Arow = Ctw + ((size_t)b * LC + c0) * D_;
    const short* Brow = Qt16 + ((size_t)b * LQ + q0) * D_;
    int lr = l >> 3, sl = l & 7;
    for (int kt = 0; kt < 2; ++kt) {
        __syncthreads();
#pragma unroll
        for (int i = 0; i < 4; ++i) {
            int r = w * 32 + i * 8 + lr;
            int g = sl ^ (r & 7);
            gll16(Arow + (size_t)r * D_ + kt * 64 + g * 8, &As[(w * 32 + i * 8) * 64]);
            gll16(Brow + (size_t)r * D_ + kt * 64 + g * 8, &Bs[(w * 32 + i * 8) * 64]);
        }
        __syncthreads();
#pragma unroll
        for (int ks = 0; ks < 2; ++ks) {
            int kg = ks * 4 + (l >> 4);
            bf16x8 af[4], bfr[4];
#pragma unroll
            for (int ms = 0; ms < 4; ++ms) {
                int m = wm_ * 64 + ms * 16 + (l & 15);
                af[ms] = *(const bf16x8*)&As[m * 64 + (kg ^ (m & 7)) * 8];
            }
#pragma unroll
            for (int ns = 0; ns < 4; ++ns) {
                int n = wn * 64 + ns * 16 + (l & 15);
                bfr[ns] = *(const bf16x8*)&Bs[n * 64 + (kg ^ (n & 7)) * 8];
            }
#pragma unroll
            for (int ms = 0; ms < 4; ++ms)
#pragma unroll
                for (int ns = 0; ns < 4; ++ns)
                    acc[ms][ns] = __builtin_amdgcn_mfma_f32_16x16x32_bf16(af[ms], bfr[ns], acc[ms][ns], 0, 0, 0);
        }
    }
    float bv = bias[0];
    float s0v[16];
    int cmv[16];
#pragma unroll
    for (int ms = 0; ms < 4; ++ms) {
        int cb = c0 + wm_ * 64 + ms * 16 + (l >> 4) * 4;
        float4 sv = *(const float4*)(s0 + b * LC + cb);
        s0v[ms * 4 + 0] = sv.x; s0v[ms * 4 + 1] = sv.y;
        s0v[ms * 4 + 2] = sv.z; s0v[ms * 4 + 3] = sv.w;
        int4 cv = *(const int4*)(Cmask + b * LC + cb);
        cmv[ms * 4 + 0] = cv.x; cmv[ms * 4 + 1] = cv.y;
        cmv[ms * 4 + 2] = cv.z; cmv[ms * 4 + 3] = cv.w;
    }
    float rs_[16];
#pragma unroll
    for (int k = 0; k < 16; ++k) rs_[k] = 0.f;
    __syncthreads();
    float* Mp = (float*)As;               // col-max partials [8][132]
    float* Lp = (float*)Bs;               // col-sum partials [8][132]
    float* Rsf = (float*)As + 2048;       // row-sum halves [2][128]
    int prow = wm_ * 4 + (l >> 4);        // 0..7
#pragma unroll
    for (int ns = 0; ns < 4; ++ns) {
        int qi = wn * 64 + ns * 16 + (l & 15);   // 0..127 within tile
        int q = q0 + qi;
        float s1v = s1[b * LQ + q] + bv;
        int qmn = Qmask[b * LQ + q];
        float vq16[16];
#pragma unroll
        for (int ms = 0; ms < 4; ++ms) {
            int cb = c0 + wm_ * 64 + ms * 16 + (l >> 4) * 4;
#pragma unroll
            for (int r = 0; r < 4; ++r) {
                float vf = acc[ms][ns][r] + s0v[ms * 4 + r] + s1v;
                _Float16 h = (_Float16)vf;
                S16[((size_t)b * LC + cb + r) * LQ + q] = h;
                vq16[ms * 4 + r] = (float)h;
            }
        }
        float mt = NEGINF;
#pragma unroll
        for (int k = 0; k < 16; ++k) mt = fmaxf(mt, cmv[k] ? vq16[k] : NEGINF);
        float st = 0.f;
#pragma unroll
        for (int k = 0; k < 16; ++k) st += cmv[k] ? __expf(vq16[k] - mt) : 0.f;
        Mp[prow * 132 + qi] = mt;
        Lp[prow * 132 + qi] = st;
#pragma unroll
        for (int k = 0; k < 16; ++k) rs_[k] += qmn ? __expf(vq16[k]) : 0.f;
    }
#pragma unroll
    for (int off = 1; off < 16; off <<= 1)
#pragma unroll
        for (int k = 0; k < 16; ++k) rs_[k] += __shfl_xor(rs_[k], off, 64);
    if ((l & 15) == 0) {
#pragma unroll
        for (int ms = 0; ms < 4; ++ms)
#pragma unroll
            for (int r = 0; r < 4; ++r) {
                int cl = wm_ * 64 + ms * 16 + (l >> 4) * 4 + r;
                Rsf[wn * 128 + cl] = rs_[ms * 4 + r];
            }
    }
    __syncthreads();
    if (t < 128) {
        float mm = Mp[t], ll = Lp[t];
#pragma unroll
        for (int g = 1; g < 8; ++g) {
            float m2 = Mp[g * 132 + t], l2 = Lp[g * 132 + t];
            float mn = fmaxf(mm, m2);
            ll = ll * __expf(mm - mn) + l2 * __expf(m2 - mn);
            mm = mn;
        }
        size_t o = ((size_t)cT * B_ + b) * LQ + q0 + t;
        pm[o] = mm; pl[o] = ll;
        size_t orow = ((size_t)qT * B_ + b) * LC + c0 + t;
        plr[orow] = Rsf[t] + Rsf[128 + t];
    }
}

// ---------- K3: combine partials ----------
__global__ void k_comb(const float* __restrict__ pm, const float* __restrict__ pl,
                       const float* __restrict__ plr,
                       float* __restrict__ colmax, float* __restrict__ colsum,
                       float* __restrict__ rowsum) {
    int bx = blockIdx.x;
    if (bx < (B_ * LQ) / 256) {
        int idx = bx * 256 + threadIdx.x;       // b*LQ + q
        float m = NEGINF, l = 0.f;
#pragma unroll
        for (int ch = 0; ch < CCH; ++ch) {
            float m2 = pm[(size_t)ch * B_ * LQ + idx];
            float l2 = pl[(size_t)ch * B_ * LQ + idx];
            float mn = fmaxf(m, m2);
            l = l * __expf(m - mn) + l2 * __expf(m2 - mn);
            m = mn;
        }
        colmax[idx] = m; colsum[idx] = l;
    } else {
        int idx = (bx - (B_ * LQ) / 256) * 256 + threadIdx.x;  // b*LC + c
        float s = 0.f;
#pragma unroll
        for (int ch = 0; ch < RCH; ++ch) s += plr[(size_t)ch * B_ * LC + idx];
        rowsum[idx] = s;
    }
}

// ---------- K5: V2 GEMM (reads raw S once per kt for the col-exp B operand) ----------
__global__ __launch_bounds__(256) void k_V2_mfma(const short* __restrict__ Cb16,
                                                 const _Float16* __restrict__ S16,
                                                 const int* __restrict__ Cmask,
                                                 const float* __restrict__ colmax,
                                                 const float* __restrict__ colsum,
                                                 short* __restrict__ Wf) {
    int b = blockIdx.y;
    int q0 = blockIdx.x * 64;
    int t = threadIdx.x, w = t >> 6, l = t & 63;
    __shared__ short As[128 * 64];
    __shared__ short Bs[64 * 72];
    f32x4 acc[2][4] = {};
    const short* Arow = Cb16 + (size_t)b * D_ * LC;
    int lr = l >> 3, sl = l & 7;
    float cmx[16];
#pragma unroll
    for (int j2 = 0; j2 < 4; ++j2)
        *(float4*)&cmx[j2 * 4] = *(const float4*)(colmax + b * LQ + q0 + w * 16 + j2 * 4);
    const _Float16* Sq = S16 + (size_t)b * LC * LQ + q0 + w * 16;
    const int* cmb = Cmask + b * LC;

    for (int kt = 0; kt < 32; ++kt) {
        int ck = kt * 64;
        __builtin_amdgcn_s_barrier();        // prev iter's LDS reads all consumed
        __builtin_amdgcn_sched_barrier(0);
#pragma unroll
        for (int i = 0; i < 4; ++i) {
            int r = w * 32 + i * 8 + lr;
            int g = sl ^ (r & 7);
            gll16(Arow + (size_t)r * LC + ck + g * 8, &As[(w * 32 + i * 8) * 64]);
        }
        {
            int c = ck + l;
            float cmf = (float)cmb[c];
            const _Float16* sp = Sq + (size_t)c * LQ;
            f16x8 v0 = *(const f16x8*)sp;
            f16x8 v1 = *(const f16x8*)(sp + 8);
#pragma unroll
            for (int j = 0; j < 8; ++j)
                Bs[(w * 16 + j) * 72 + l] = (short)bf16rne(cmf * __expf((float)v0[j] - cmx[j]));
#pragma unroll
            for (int j = 0; j < 8; ++j)
                Bs[(w * 16 + 8 + j) * 72 + l] = (short)bf16rne(cmf * __expf((float)v1[j] - cmx[8 + j]));
        }
        asm volatile("s_waitcnt vmcnt(0) lgkmcnt(0)" ::: "memory");
        __builtin_amdgcn_s_barrier();
        __builtin_amdgcn_sched_barrier(0);
#pragma unroll
        for (int ks = 0; ks < 2; ++ks) {
            int kg = ks * 4 + (l >> 4);
            bf16x8 af[2], bfr[4];
#pragma unroll
            for (int ms = 0; ms < 2; ++ms) {
                int m = w * 32 + ms * 16 + (l & 15);
                af[ms] = *(const bf16x8*)&As[m * 64 + (kg ^ (m & 7)) * 8];
            }
#pragma unroll
            for (int ns = 0; ns < 4; ++ns) {
                int n = ns * 16 + (l & 15);
                bfr[ns] = *(const bf16x8*)&Bs[n * 72 + kg * 8];
            }
#pragma unroll
            for (int ms = 0; ms < 2; ++ms)
#pragma unroll
                for (int ns = 0; ns < 4; ++ns)
                    acc[ms][ns] = __builtin_amdgcn_mfma_f32_16x16x32_bf16(af[ms], bfr[ns], acc[ms][ns], 0, 0, 0);
        }
    }
#pragma unroll
    for (int ms = 0; ms < 2; ++ms)
#pragma unroll
        for (int ns = 0; ns < 4; ++ns) {
            int q = q0 + ns * 16 + (l & 15);
            float csi = 1.0f / colsum[b * LQ + q];
#pragma unroll
            for (int r = 0; r < 4; ++r) {
                int dd = w * 32 + ms * 16 + (l >> 4) * 4 + r;
                Wf[((size_t)b * 256 + 128 + dd) * LQ + q] = (short)bf16rne(acc[ms][ns][r] * csi);
            }
        }
}

// ---------- K6: OUT^T GEMM. A(Wf) gll16 double-buffered; B = P1 on the fly from
// raw S16 (reg-staged). CHANGES vs r10: Bs SINGLE-buffered (safe: written from
// regs after the prev-iter-end barrier, read after this iter's barrier) and the
// Qmask LDS table replaced by a per-thread 64-bit mask register.
// LDS = 64K (As x2) + 16K (Bs) = exactly 80 KB -> 2 blocks/CU. ----------
__global__ __launch_bounds__(512) void k_out_mfma(const _Float16* __restrict__ S16,
                                                  const short* __restrict__ Wf,
                                                  const float* __restrict__ C,
                                                  const int* __restrict__ Qmask,
                                                  const float* __restrict__ rowsum,
                                                  float* __restrict__ out) {
    int b = blockIdx.y;
    int c0 = blockIdx.x * 128;
    int t = threadIdx.x, w = t >> 6, l = t & 63;
    int wn = w & 3, wc = w >> 2;            // wave tile: n = wn*64.., c = wc*64..
    __shared__ short As[2 * 256 * 64];       // Wf rows (n), 2 x 32 KB
    __shared__ short Bs[128 * 64];           // P1 rows (c), 16 KB  -> 80 KB total
    f32x4 acc[4][4] = {};
    const short* Arow = Wf + (size_t)b * 256 * LQ;
    const _Float16* Brow = S16 + ((size_t)b * LC + c0) * LQ;
    int lr = l >> 3, sl = l & 7;
    int g = sl ^ lr;                         // staging swizzle (row&7 == lr)
    // B thread-fixed rows + their 1/rowsum (constant across kt)
    int r0 = w * 16 + lr, r1 = r0 + 8;
    float ri0 = 1.0f / rowsum[b * LC + c0 + r0];
    float ri1 = 1.0f / rowsum[b * LC + c0 + r1];
    // Qmask bits for this thread's q-slots: bit (kt*8+j) = Qmask[kt*64 + g*8 + j]
    unsigned long long qbits = 0ull;
#pragma unroll
    for (int kt = 0; kt < 8; ++kt) {
        const int* qp = Qmask + b * LQ + kt * 64 + g * 8;
        int4 qa = *(const int4*)qp;
        int4 qb = *(const int4*)(qp + 4);
        unsigned bits = (qa.x ? 1u : 0u) | (qa.y ? 2u : 0u) | (qa.z ? 4u : 0u) | (qa.w ? 8u : 0u)
                      | (qb.x ? 16u : 0u) | (qb.y ? 32u : 0u) | (qb.z ? 64u : 0u) | (qb.w ? 128u : 0u);
        qbits |= (unsigned long long)bits << (kt * 8);
    }

#define STAGE_A(p, kt)                                                            \
    {                                                                             \
        short* Ad = As + (p) * (256 * 64);                                        \
        _Pragma("unroll")                                                         \
        for (int i = 0; i < 4; ++i) {                                             \
            int r = w * 32 + i * 8 + lr;                                          \
            gll16(Arow + (size_t)r * LQ + (kt) * 64 + g * 8,                      \
                  &Ad[(w * 32 + i * 8) * 64]);                                    \
        }                                                                         \
    }
#define LOAD_B(v0_, v1_, kt)                                                      \
    v0_ = *(const f16x8*)(Brow + (size_t)r0 * LQ + (kt) * 64 + g * 8);            \
    v1_ = *(const f16x8*)(Brow + (size_t)r1 * LQ + (kt) * 64 + g * 8);

    f16x8 bA0, bA1, bB0, bB1;                // two tiles of B regs in flight
    LOAD_B(bA0, bA1, 0);
    STAGE_A(0, 0);
    LOAD_B(bB0, bB1, 1);
    STAGE_A(1, 1);
    __builtin_amdgcn_sched_barrier(0);
    int cur = 0;
    for (int kt = 0; kt < 8; ++kt) {
        if (kt < 7) asm volatile("s_waitcnt vmcnt(6)" ::: "memory");  // this tile's B+A done
        else        asm volatile("s_waitcnt vmcnt(0)" ::: "memory");
        // build P1 tile in LDS from regs: p = qm ? exp(S)*ri : 0
        // (safe single-buffer: all reads of Bs from iter kt-1 completed at the
        //  end-of-iter barrier every wave passed before reaching here)
        {
            f16x8 v0 = (kt & 1) ? bB0 : bA0;
            f16x8 v1 = (kt & 1) ? bB1 : bA1;
            unsigned bits = (unsigned)(qbits >> (kt * 8)) & 0xffu;
            unsigned short p0[8], p1[8];
#pragma unroll
            for (int j = 0; j < 8; ++j)
                p0[j] = (bits >> j) & 1u ? bf16rne(__expf((float)v0[j]) * ri0) : (unsigned short)0;
#pragma unroll
            for (int j = 0; j < 8; ++j)
                p1[j] = (bits >> j) & 1u ? bf16rne(__expf((float)v1[j]) * ri1) : (unsigned short)0;
            *(us8*)&Bs[r0 * 64 + sl * 8] = *(const us8*)&p0[0];
            *(us8*)&Bs[r1 * 64 + sl * 8] = *(const us8*)&p1[0];
        }
        asm volatile("s_waitcnt lgkmcnt(0)" ::: "memory");
        __builtin_amdgcn_s_barrier();
        __builtin_amdgcn_sched_barrier(0);
        const short* Ac = As + cur * (256 * 64);
#pragma unroll
        for (int ks = 0; ks < 2; ++ks) {
            int kg = ks * 4 + (l >> 4);
            bf16x8 af[4], bfr[4];
#pragma unroll
            for (int ms = 0; ms < 4; ++ms) {
                int m = wn * 64 + ms * 16 + (l & 15);
                af[ms] = *(const bf16x8*)&Ac[m * 64 + (kg ^ (m & 7)) * 8];
            }
#pragma unroll
            for (int ns = 0; ns < 4; ++ns) {
                int cc = wc * 64 + ns * 16 + (l & 15);
                bfr[ns] = *(const bf16x8*)&Bs[cc * 64 + (kg ^ (cc & 7)) * 8];
            }
#pragma unroll
            for (int ms = 0; ms < 4; ++ms)
#pragma unroll
                for (int ns = 0; ns < 4; ++ns)
                    acc[ms][ns] = __builtin_amdgcn_mfma_f32_16x16x32_bf16(af[ms], bfr[ns], acc[ms][ns], 0, 0, 0);
        }
        __builtin_amdgcn_s_barrier();        // all waves done reading As[cur]+Bs
        __builtin_amdgcn_sched_barrier(0);
        if (kt < 6) {
            if (kt & 1) { LOAD_B(bB0, bB1, kt + 2); }
            else        { LOAD_B(bA0, bA1, kt + 2); }
            STAGE_A(cur, kt + 2);
        }
        cur ^= 1;
    }
#undef STAGE_A
#undef LOAD_B
#pragma unroll
    for (int ms = 0; ms < 4; ++ms) {
        int nb = wn * 64 + ms * 16 + (l >> 4) * 4;
#pragma unroll
        for (int ns = 0; ns < 4; ++ns) {
            int c = c0 + wc * 64 + ns * 16 + (l & 15);
#pragma unroll
            for (int r = 0; r < 4; ++r) {
                int n = nb + r;
                float a = acc[ms][ns][r];
                if (n < 128) {
                    float cv = C[((size_t)b * D_ + n) * LC + c];
                    out[((size_t)b * 512 + n) * LC + c] = cv;          // plane 0: Ct
                    out[((size_t)b * 512 + 128 + n) * LC + c] = a;     // plane 1: A
                    out[((size_t)b * 512 + 256 + n) * LC + c] = cv * a;// plane 2: Ct*A
                } else {
                    int dd = n - 128;
                    float cv = C[((size_t)b * D_ + dd) * LC + c];
                    out[((size_t)b * 512 + 384 + dd) * LC + c] = cv * a;// plane 3: Ct*Bm
                }
            }
        }
    }
}

extern "C" void kernel_launch(void* const* d_in, const int* in_sizes, int n_in,
                              void* d_out, int out_size, void* d_ws, size_t ws_size,
                              hipStream_t stream) {
    const float* C     = (const float*)d_in[0];
    const float* Q     = (const float*)d_in[1];
    const int*   Cmask = (const int*)d_in[2];
    const int*   Qmask = (const int*)d_in[3];
    const float* w_c   = (const float*)d_in[4];
    const float* w_q   = (const float*)d_in[5];
    const float* w_mul = (const float*)d_in[6];
    const float* bias  = (const float*)d_in[7];
    float* out = (float*)d_out;

    _Float16* S16 = (_Float16*)d_ws;                      // B*LC*LQ fp16  = 67.1 MB (stays RAW)
    short* Cb16 = (short*)(S16 + (size_t)B_ * LC * LQ);   // B*D*LC bf16   = 16.8 MB
    short* Ctw  = Cb16 + (size_t)B_ * D_ * LC;            // B*LC*D bf16   = 16.8 MB
    short* Qt16 = Ctw + (size_t)B_ * LC * D_;             // B*LQ*D bf16   =  4.2 MB
    short* Wf   = Qt16 + (size_t)B_ * LQ * D_;            // B*256*LQ bf16 =  8.4 MB
    float* s0     = (float*)(Wf + (size_t)B_ * 256 * LQ); // B*LC
    float* s1     = s0 + B_ * LC;                         // B*LQ
    float* colmax = s1 + B_ * LQ;                         // B*LQ
    float* colsum = colmax + B_ * LQ;                     // B*LQ
    float* rowsum = colsum + B_ * LQ;                     // B*LC
    float* pm     = rowsum + B_ * LC;                     // CCH*B*LQ = 1 MB
    float* pl     = pm + (size_t)CCH * B_ * LQ;           // CCH*B*LQ = 1 MB
    float* plr    = pl + (size_t)CCH * B_ * LQ;           // RCH*B*LC = 1 MB

    hipLaunchKernelGGL(k_dotw, dim3(B_ * LC / 256), dim3(256), 0, stream, C, w_c, s0, LC);
    hipLaunchKernelGGL(k_dotw, dim3(B_ * LQ / 256), dim3(256), 0, stream, Q, w_q, s1, LQ);
    hipLaunchKernelGGL(k_prep_C, dim3(LC / 64, B_), dim3(256), 0, stream, C, w_mul, Ctw, Cb16);
    hipLaunchKernelGGL(k_prep_Q, dim3(LQ / 64, B_), dim3(256), 0, stream, Q, Qt16, Wf);
    // k_S emits S16 + col partials (pm/pl) + row-sum partials (plr)
    hipLaunchKernelGGL(k_S_mfma, dim3((LC / 128) * (LQ / 128), B_), dim3(256), 0, stream,
                       Ctw, Qt16, s0, s1, bias, Cmask, Qmask, S16, pm, pl, plr);
    hipLaunchKernelGGL(k_comb, dim3((B_ * LQ + B_ * LC) / 256), dim3(256), 0, stream,
                       pm, pl, plr, colmax, colsum, rowsum);
    // V2 GEMM (reads raw S; no P1 writeback)
    hipLaunchKernelGGL(k_V2_mfma, dim3(LQ / 64, B_), dim3(256), 0, stream,
                       Cb16, S16, Cmask, colmax, colsum, Wf);
    // OUT GEMM computes row-softmax on the fly from raw S16
    hipLaunchKernelGGL(k_out_mfma, dim3(LC / 128, B_), dim3(512), 0, stream,
                       S16, Wf, C, Qmask, rowsum, out);
}